// Round 7
// baseline (154.947 us; speedup 1.0000x reference)
//
#include <hip/hip_runtime.h>

#define TOKENS 4096
#define HIDDEN 4096
#define FFN    14336
#define SCALING 2.0f

typedef short short8 __attribute__((ext_vector_type(8)));
typedef float f32x16 __attribute__((ext_vector_type(16)));

// ---------------------------------------------------------------------------
// 32x32x16 MFMA fragment layouts (HW-verified m74/m101):
//   A frag: lane l (m=l&31, h=l>>5) holds 8 bf16: row m, k = 8h+i
//   B frag: lane l (n=l&31, h=l>>5) holds 8 bf16: col n, k = 8h+i
//   C/D frag: lane l, reg j: row = (j&3)+8*(j>>2)+4h, col = l&31
// v_permlane32_swap_b32 DST,SRC swaps DST.lanes[32:63] <-> SRC.lanes[0:31].
//
// ws layout (bytes):
#define OFF_W1BPK  ((size_t)0)         // [448 f-tiles][64][8 bf16]  2*w1B (A-frag m=f,k=r)
#define OFF_W3BPK  ((size_t)458752)    // [448][64][8]               2*w3B
#define OFF_W2APK  ((size_t)917504)    // [896 16f-subtiles][64][8]  w2A (B-frag k=f,n=r; n>=16 zero)
#define OFF_B1PK   ((size_t)1835008)   // [448][2 halves][16 f32]    2*w1Bb in C-frag order
#define OFF_B3PK   ((size_t)1892352)   // [448][2][16]               2*w3Bb
#define OFF_SLAB   ((size_t)1949696)   // [8 splits][4096][32] f32   k1 partial x-proj (no bias)
#define OFF_H2S    ((size_t)6144000)   // [28 chunks][4096][16] f32  k2 partial h2
// end 13484032 (13.5 MB; ws is >=256 MB per harness poison fill)

#define K1_SPLITS 8
#define K2_CHUNKS 28

__device__ __forceinline__ uint32_t pk_bf16(float a, float b) {
    uint32_t r;
    asm("v_cvt_pk_bf16_f32 %0, %1, %2" : "=v"(r) : "v"(a), "v"(b));
    return r;
}

// ---------------- P0: pack k2 weights/biases to fragment layouts ------------
__global__ __launch_bounds__(256) void p0_pack(
    const float* __restrict__ w1B, const float* __restrict__ w3B,
    const float* __restrict__ w2A,
    const float* __restrict__ w1Bb, const float* __restrict__ w3Bb,
    char* __restrict__ ws)
{
    const int g = blockIdx.x * 256 + threadIdx.x;

    if (g < 28672) {                       // w1bpk: [ft][l] <- 2*w1B[f=ft*32+c][r=8h+i]
        int l = g & 63, ft = g >> 6, c = l & 31, h = l >> 5;
        const float* s = w1B + (size_t)(ft * 32 + c) * 16 + 8 * h;
        float4 a = *(const float4*)s, b = *(const float4*)(s + 4);
        uint4 o = make_uint4(pk_bf16(a.x * 2.f, a.y * 2.f), pk_bf16(a.z * 2.f, a.w * 2.f),
                             pk_bf16(b.x * 2.f, b.y * 2.f), pk_bf16(b.z * 2.f, b.w * 2.f));
        ((uint4*)(ws + OFF_W1BPK))[g] = o;
    } else if (g < 57344) {                // w3bpk
        int t = g - 28672, l = t & 63, ft = t >> 6, c = l & 31, h = l >> 5;
        const float* s = w3B + (size_t)(ft * 32 + c) * 16 + 8 * h;
        float4 a = *(const float4*)s, b = *(const float4*)(s + 4);
        uint4 o = make_uint4(pk_bf16(a.x * 2.f, a.y * 2.f), pk_bf16(a.z * 2.f, a.w * 2.f),
                             pk_bf16(b.x * 2.f, b.y * 2.f), pk_bf16(b.z * 2.f, b.w * 2.f));
        ((uint4*)(ws + OFF_W3BPK))[t] = o;
    } else if (g < 114688) {               // w2apk: [st][l] <- w2A[r=c][f=st*16+8h+i], zero c>=16
        int t = g - 57344, l = t & 63, st = t >> 6, c = l & 31, h = l >> 5;
        uint4 o = make_uint4(0u, 0u, 0u, 0u);
        if (c < 16) {
            const float* s = w2A + (size_t)c * FFN + st * 16 + 8 * h;
            float4 a = *(const float4*)s, b = *(const float4*)(s + 4);
            o = make_uint4(pk_bf16(a.x, a.y), pk_bf16(a.z, a.w),
                           pk_bf16(b.x, b.y), pk_bf16(b.z, b.w));
        }
        ((uint4*)(ws + OFF_W2APK))[t] = o;
    } else if (g < 129024) {               // b1pk: [ft][h][j] = 2*w1Bb[ft*32+(j&3)+8*(j>>2)+4h]
        int t = g - 114688, ft = t >> 5, rest = t & 31, h = rest >> 4, j = rest & 15;
        int f = ft * 32 + (j & 3) + 8 * (j >> 2) + 4 * h;
        ((float*)(ws + OFF_B1PK))[t] = 2.f * w1Bb[f];
    } else if (g < 143360) {               // b3pk
        int t = g - 129024, ft = t >> 5, rest = t & 31, h = rest >> 4, j = rest & 15;
        int f = ft * 32 + (j & 3) + 8 * (j >> 2) + 4 * h;
        ((float*)(ws + OFF_B3PK))[t] = 2.f * w3Bb[f];
    }
}

// ---------------- K1: x-projection via MFMA, W packed inline ----------------
// 4 waves/block share one 32-token tile; K split 8-way (grid.y) x 4-way
// (waves), 8 k-tiles each. 1024 blocks -> 16 waves/CU for latency hiding.
__global__ __launch_bounds__(256, 2) void k1_xproj(
    const float* __restrict__ x,
    const float* __restrict__ w1A, const float* __restrict__ w3A,
    float* __restrict__ slab)
{
    __shared__ float s_red[4][32][32];   // 16 KB
    const int tid = threadIdx.x;
    const int w = tid >> 6, l = tid & 63, c = l & 31, h = l >> 5;
    const int t0 = blockIdx.x * 32;
    const int by = blockIdx.y;

    f32x16 acc;
    #pragma unroll
    for (int j = 0; j < 16; ++j) acc[j] = 0.f;

    const float* xr = x + (size_t)(t0 + c) * HIDDEN + 8 * h;
    const float* wr = ((c < 16) ? (w1A + (size_t)c * HIDDEN)
                                : (w3A + (size_t)(c - 16) * HIDDEN)) + 8 * h;
    const int kt0 = by * 32 + w * 8;
    #pragma unroll 4
    for (int kt = kt0; kt < kt0 + 8; ++kt) {
        const float* xp = xr + (size_t)kt * 16;
        const float* wp = wr + (size_t)kt * 16;
        float4 a0 = *(const float4*)xp, a1 = *(const float4*)(xp + 4);
        float4 b0 = *(const float4*)wp, b1 = *(const float4*)(wp + 4);
        short8 av = __builtin_bit_cast(short8,
            make_uint4(pk_bf16(a0.x, a0.y), pk_bf16(a0.z, a0.w),
                       pk_bf16(a1.x, a1.y), pk_bf16(a1.z, a1.w)));
        short8 bv = __builtin_bit_cast(short8,
            make_uint4(pk_bf16(b0.x, b0.y), pk_bf16(b0.z, b0.w),
                       pk_bf16(b1.x, b1.y), pk_bf16(b1.z, b1.w)));
        acc = __builtin_amdgcn_mfma_f32_32x32x16_bf16(av, bv, acc, 0, 0, 0);
    }
    #pragma unroll
    for (int j = 0; j < 16; ++j) {
        int row = (j & 3) + 8 * (j >> 2) + 4 * h;
        s_red[w][row][c] = acc[j];
    }
    __syncthreads();
    float* sl = slab + (size_t)by * TOKENS * 32;
    for (int p = tid; p < 1024; p += 256) {
        int row = p >> 5, cc = p & 31;
        float s = s_red[0][row][cc] + s_red[1][row][cc]
                + s_red[2][row][cc] + s_red[3][row][cc];
        sl[(size_t)(t0 + row) * 32 + cc] = s;
    }
}

// ---------------- K2: fused mid (slab->frag, mfma1, silu, permlane, mfma2) --
// grid (128 token-tiles, 28 f-chunks) = 3584 blocks; 4 f-tiles per wave.
__global__ __launch_bounds__(256, 6) void k2_mid(
    const float* __restrict__ slab,
    const float* __restrict__ w1Ab, const float* __restrict__ w3Ab,
    const uint4* __restrict__ w1bpk, const uint4* __restrict__ w3bpk,
    const uint4* __restrict__ w2apk,
    const float* __restrict__ b1pk, const float* __restrict__ b3pk,
    float* __restrict__ h2s)
{
    __shared__ float s_acc[4][32][16];
    const int tid = threadIdx.x;
    const int w = tid >> 6, l = tid & 63, c = l & 31, h = l >> 5;
    const int tt = blockIdx.x, t0 = tt * 32, by = blockIdx.y;

    // Build h13 B-fragments from the 8 slabs + A-bias.
    // B-frag lane (c,h): col n = token t0+c, k = r = 8h+i.
    float a[8], b[8];
    {
        float4 a0 = *(const float4*)(w1Ab + 8 * h), a1 = *(const float4*)(w1Ab + 8 * h + 4);
        float4 b0 = *(const float4*)(w3Ab + 8 * h), b1 = *(const float4*)(w3Ab + 8 * h + 4);
        a[0]=a0.x; a[1]=a0.y; a[2]=a0.z; a[3]=a0.w; a[4]=a1.x; a[5]=a1.y; a[6]=a1.z; a[7]=a1.w;
        b[0]=b0.x; b[1]=b0.y; b[2]=b0.z; b[3]=b0.w; b[4]=b1.x; b[5]=b1.y; b[6]=b1.z; b[7]=b1.w;
    }
    #pragma unroll
    for (int s = 0; s < K1_SPLITS; ++s) {
        const float* p = slab + ((size_t)s * TOKENS + t0 + c) * 32 + 8 * h;
        float4 v0 = *(const float4*)p,        v1 = *(const float4*)(p + 4);
        float4 u0 = *(const float4*)(p + 16), u1 = *(const float4*)(p + 20);
        a[0]+=v0.x; a[1]+=v0.y; a[2]+=v0.z; a[3]+=v0.w;
        a[4]+=v1.x; a[5]+=v1.y; a[6]+=v1.z; a[7]+=v1.w;
        b[0]+=u0.x; b[1]+=u0.y; b[2]+=u0.z; b[3]+=u0.w;
        b[4]+=u1.x; b[5]+=u1.y; b[6]+=u1.z; b[7]+=u1.w;
    }
    const short8 hA8 = __builtin_bit_cast(short8,
        make_uint4(pk_bf16(a[0],a[1]), pk_bf16(a[2],a[3]),
                   pk_bf16(a[4],a[5]), pk_bf16(a[6],a[7])));
    const short8 hB8 = __builtin_bit_cast(short8,
        make_uint4(pk_bf16(b[0],b[1]), pk_bf16(b[2],b[3]),
                   pk_bf16(b[4],b[5]), pk_bf16(b[6],b[7])));

    f32x16 acc;
    #pragma unroll
    for (int j = 0; j < 16; ++j) acc[j] = 0.f;

    #pragma unroll 2
    for (int it = 0; it < 4; ++it) {
        const int ft = by * 16 + w * 4 + it;
        short8 a1g = __builtin_bit_cast(short8, w1bpk[(size_t)ft * 64 + l]);
        short8 a1u = __builtin_bit_cast(short8, w3bpk[(size_t)ft * 64 + l]);
        short8 b2a = __builtin_bit_cast(short8, w2apk[(size_t)(ft * 2) * 64 + l]);
        short8 b2b = __builtin_bit_cast(short8, w2apk[(size_t)(ft * 2 + 1) * 64 + l]);

        f32x16 Cg = *reinterpret_cast<const f32x16*>(b1pk + ((size_t)ft * 2 + h) * 16);
        f32x16 Cu = *reinterpret_cast<const f32x16*>(b3pk + ((size_t)ft * 2 + h) * 16);

        // D1[f][token] with bias as C-init; weights pre-scaled by 2
        f32x16 d1g = __builtin_amdgcn_mfma_f32_32x32x16_bf16(a1g, hA8, Cg, 0, 0, 0);
        f32x16 d1u = __builtin_amdgcn_mfma_f32_32x32x16_bf16(a1u, hB8, Cu, 0, 0, 0);

        float hv[16];
        #pragma unroll
        for (int j = 0; j < 16; ++j) {
            float gg = d1g[j];
            float sig = __builtin_amdgcn_rcpf(1.f + __expf(-gg));
            hv[j] = gg * sig * d1u[j];
        }
        uint32_t q0 = pk_bf16(hv[0], hv[1]),   q1 = pk_bf16(hv[2], hv[3]);
        uint32_t q2 = pk_bf16(hv[4], hv[5]),   q3 = pk_bf16(hv[6], hv[7]);
        uint32_t q4 = pk_bf16(hv[8], hv[9]),   q5 = pk_bf16(hv[10], hv[11]);
        uint32_t q6 = pk_bf16(hv[12], hv[13]), q7 = pk_bf16(hv[14], hv[15]);
        // DST.high <-> SRC.low: q0=[h0:f01|h1:f89]=A2 reg0, q2=[h0:f45|h1:f1213]=reg2, ...
        asm("v_permlane32_swap_b32 %0, %1" : "+v"(q0), "+v"(q2));
        asm("v_permlane32_swap_b32 %0, %1" : "+v"(q1), "+v"(q3));
        asm("v_permlane32_swap_b32 %0, %1" : "+v"(q4), "+v"(q6));
        asm("v_permlane32_swap_b32 %0, %1" : "+v"(q5), "+v"(q7));
        short8 a2a = __builtin_bit_cast(short8, make_uint4(q0, q1, q2, q3));
        short8 a2b = __builtin_bit_cast(short8, make_uint4(q4, q5, q6, q7));

        acc = __builtin_amdgcn_mfma_f32_32x32x16_bf16(a2a, b2a, acc, 0, 0, 0);
        acc = __builtin_amdgcn_mfma_f32_32x32x16_bf16(a2b, b2b, acc, 0, 0, 0);
    }

    if (c < 16) {
        #pragma unroll
        for (int j = 0; j < 16; ++j)
            s_acc[w][(j & 3) + 8 * (j >> 2) + 4 * h][c] = acc[j];
    }
    __syncthreads();
    for (int p = tid; p < 512; p += 256) {
        int tok = p >> 4, r = p & 15;
        float s = s_acc[0][tok][r] + s_acc[1][tok][r] + s_acc[2][tok][r] + s_acc[3][tok][r];
        h2s[((size_t)by * TOKENS + t0 + tok) * 16 + r] = s;
    }
}

// ---------------- K3: out = ((sum_chunks h2 + w2Ab) @ w2B.T + w2Bb) * 2 -----
__global__ __launch_bounds__(256) void k3_out(
    const float* __restrict__ h2s,
    const float* __restrict__ w2Ab,
    const float* __restrict__ w2B, const float* __restrict__ w2Bb,
    float* __restrict__ out)
{
    __shared__ float s_h2[16][16];
    const int tid = threadIdx.x;
    const int t0 = blockIdx.x * 16;
    const int o0 = blockIdx.y * 1024;

    {
        int t = tid >> 4, r = tid & 15;
        float a = w2Ab[r];
        #pragma unroll 4
        for (int s = 0; s < K2_CHUNKS; ++s)
            a += h2s[((size_t)s * TOKENS + t0 + t) * 16 + r];
        s_h2[t][r] = a;
    }
    __syncthreads();

    const int ob = o0 + tid * 4;
    float w[4][16];
    #pragma unroll
    for (int j = 0; j < 4; ++j) {
        #pragma unroll
        for (int k = 0; k < 4; ++k) {
            float4 v = *(const float4*)(w2B + (size_t)(ob + j) * 16 + k * 4);
            w[j][4*k+0] = v.x; w[j][4*k+1] = v.y;
            w[j][4*k+2] = v.z; w[j][4*k+3] = v.w;
        }
    }
    float4 bb = *(const float4*)(w2Bb + ob);
    float bias[4] = {bb.x, bb.y, bb.z, bb.w};

    for (int t = 0; t < 16; ++t) {
        float res[4];
        #pragma unroll
        for (int j = 0; j < 4; ++j) {
            float a = bias[j];
            #pragma unroll
            for (int r = 0; r < 16; ++r)
                a = fmaf(s_h2[t][r], w[j][r], a);
            res[j] = a * SCALING;
        }
        *(float4*)(out + (size_t)(t0 + t) * 4096 + ob) =
            make_float4(res[0], res[1], res[2], res[3]);
    }
}

extern "C" void kernel_launch(void* const* d_in, const int* in_sizes, int n_in,
                              void* d_out, int out_size, void* d_ws, size_t ws_size,
                              hipStream_t stream) {
    const float* x    = (const float*)d_in[0];
    const float* w1A  = (const float*)d_in[1];
    const float* w1Ab = (const float*)d_in[2];
    const float* w1B  = (const float*)d_in[3];
    const float* w1Bb = (const float*)d_in[4];
    const float* w3A  = (const float*)d_in[5];
    const float* w3Ab = (const float*)d_in[6];
    const float* w3B  = (const float*)d_in[7];
    const float* w3Bb = (const float*)d_in[8];
    const float* w2A  = (const float*)d_in[9];
    const float* w2Ab = (const float*)d_in[10];
    const float* w2B  = (const float*)d_in[11];
    const float* w2Bb = (const float*)d_in[12];
    float* out = (float*)d_out;

    char* ws = (char*)d_ws;
    const uint4* w1bpk = (const uint4*)(ws + OFF_W1BPK);
    const uint4* w3bpk = (const uint4*)(ws + OFF_W3BPK);
    const uint4* w2apk = (const uint4*)(ws + OFF_W2APK);
    const float* b1pk  = (const float*)(ws + OFF_B1PK);
    const float* b3pk  = (const float*)(ws + OFF_B3PK);
    float* slab  = (float*)(ws + OFF_SLAB);
    float* h2s   = (float*)(ws + OFF_H2S);

    p0_pack<<<560, 256, 0, stream>>>(w1B, w3B, w2A, w1Bb, w3Bb, ws);
    k1_xproj<<<dim3(128, K1_SPLITS), 256, 0, stream>>>(x, w1A, w3A, slab);
    k2_mid<<<dim3(128, K2_CHUNKS), 256, 0, stream>>>(slab, w1Ab, w3Ab,
                                             w1bpk, w3bpk, w2apk, b1pk, b3pk, h2s);
    k3_out<<<dim3(256, 4), 256, 0, stream>>>(h2s, w2Ab, w2B, w2Bb, out);
}

// Round 8
// 115.309 us; speedup vs baseline: 1.3437x; 1.3437x over previous
//
#include <hip/hip_runtime.h>

#define TOKENS 4096
#define HIDDEN 4096
#define FFN    14336
#define SCALING 2.0f

typedef short short8 __attribute__((ext_vector_type(8)));
typedef float f32x16 __attribute__((ext_vector_type(16)));

// ---------------------------------------------------------------------------
// 32x32x16 MFMA fragment layouts (HW-verified m74/m101):
//   A frag: lane l (m=l&31, h=l>>5) holds 8 bf16: row m, k = 8h+i
//   B frag: lane l (n=l&31, h=l>>5) holds 8 bf16: col n, k = 8h+i
//   C/D frag: lane l, reg j: row = (j&3)+8*(j>>2)+4h, col = l&31
// v_permlane32_swap_b32 DST,SRC swaps DST.lanes[32:63] <-> SRC.lanes[0:31].
//
// ws layout (bytes):
#define OFF_W1BPK  ((size_t)0)         // [448 f-tiles][64][8 bf16]  2*w1B (A-frag m=f,k=r)
#define OFF_W3BPK  ((size_t)458752)    // [448][64][8]               2*w3B
#define OFF_W2APK  ((size_t)917504)    // [896 16f-subtiles][64][8]  w2A (B-frag k=f,n=r; n>=16 zero)
#define OFF_B1PK   ((size_t)1835008)   // [448][2 halves][16 f32]    2*w1Bb in C-frag order
#define OFF_B3PK   ((size_t)1892352)   // [448][2][16]               2*w3Bb
#define OFF_H13PK  ((size_t)1949696)   // [128 tok-tiles][64][2][8 bf16] h13 B-frags (k1b out)
#define OFF_SLAB   ((size_t)2211840)   // [8 splits][4096][32] f32   k1 partial x-proj (no bias)
#define OFF_H2S    ((size_t)6406144)   // [28 chunks][4096][16] f32  k2 partial h2
// end 13746176 (13.7 MB)

#define K1_SPLITS 8
#define K2_CHUNKS 28

__device__ __forceinline__ uint32_t pk_bf16(float a, float b) {
    uint32_t r;
    asm("v_cvt_pk_bf16_f32 %0, %1, %2" : "=v"(r) : "v"(a), "v"(b));
    return r;
}

// ---------------- P0: pack k2 weights/biases to fragment layouts ------------
__global__ __launch_bounds__(256) void p0_pack(
    const float* __restrict__ w1B, const float* __restrict__ w3B,
    const float* __restrict__ w2A,
    const float* __restrict__ w1Bb, const float* __restrict__ w3Bb,
    char* __restrict__ ws)
{
    const int g = blockIdx.x * 256 + threadIdx.x;

    if (g < 28672) {                       // w1bpk: [ft][l] <- 2*w1B[f=ft*32+c][r=8h+i]
        int l = g & 63, ft = g >> 6, c = l & 31, h = l >> 5;
        const float* s = w1B + (size_t)(ft * 32 + c) * 16 + 8 * h;
        float4 a = *(const float4*)s, b = *(const float4*)(s + 4);
        uint4 o = make_uint4(pk_bf16(a.x * 2.f, a.y * 2.f), pk_bf16(a.z * 2.f, a.w * 2.f),
                             pk_bf16(b.x * 2.f, b.y * 2.f), pk_bf16(b.z * 2.f, b.w * 2.f));
        ((uint4*)(ws + OFF_W1BPK))[g] = o;
    } else if (g < 57344) {                // w3bpk
        int t = g - 28672, l = t & 63, ft = t >> 6, c = l & 31, h = l >> 5;
        const float* s = w3B + (size_t)(ft * 32 + c) * 16 + 8 * h;
        float4 a = *(const float4*)s, b = *(const float4*)(s + 4);
        uint4 o = make_uint4(pk_bf16(a.x * 2.f, a.y * 2.f), pk_bf16(a.z * 2.f, a.w * 2.f),
                             pk_bf16(b.x * 2.f, b.y * 2.f), pk_bf16(b.z * 2.f, b.w * 2.f));
        ((uint4*)(ws + OFF_W3BPK))[t] = o;
    } else if (g < 114688) {               // w2apk: [st][l] <- w2A[r=c][f=st*16+8h+i], zero c>=16
        int t = g - 57344, l = t & 63, st = t >> 6, c = l & 31, h = l >> 5;
        uint4 o = make_uint4(0u, 0u, 0u, 0u);
        if (c < 16) {
            const float* s = w2A + (size_t)c * FFN + st * 16 + 8 * h;
            float4 a = *(const float4*)s, b = *(const float4*)(s + 4);
            o = make_uint4(pk_bf16(a.x, a.y), pk_bf16(a.z, a.w),
                           pk_bf16(b.x, b.y), pk_bf16(b.z, b.w));
        }
        ((uint4*)(ws + OFF_W2APK))[t] = o;
    } else if (g < 129024) {               // b1pk: [ft][h][j] = 2*w1Bb[ft*32+(j&3)+8*(j>>2)+4h]
        int t = g - 114688, ft = t >> 5, rest = t & 31, h = rest >> 4, j = rest & 15;
        int f = ft * 32 + (j & 3) + 8 * (j >> 2) + 4 * h;
        ((float*)(ws + OFF_B1PK))[t] = 2.f * w1Bb[f];
    } else if (g < 143360) {               // b3pk
        int t = g - 129024, ft = t >> 5, rest = t & 31, h = rest >> 4, j = rest & 15;
        int f = ft * 32 + (j & 3) + 8 * (j >> 2) + 4 * h;
        ((float*)(ws + OFF_B3PK))[t] = 2.f * w3Bb[f];
    }
}

// ---------------- K1: x-projection via MFMA, W packed inline ----------------
// 4 waves/block share one 32-token tile; K split 8-way (grid.y) x 4-way
// (waves), 8 k-tiles each. 1024 blocks -> 16 waves/CU for latency hiding.
__global__ __launch_bounds__(256, 2) void k1_xproj(
    const float* __restrict__ x,
    const float* __restrict__ w1A, const float* __restrict__ w3A,
    float* __restrict__ slab)
{
    __shared__ float s_red[4][32][32];   // 16 KB
    const int tid = threadIdx.x;
    const int w = tid >> 6, l = tid & 63, c = l & 31, h = l >> 5;
    const int t0 = blockIdx.x * 32;
    const int by = blockIdx.y;

    f32x16 acc;
    #pragma unroll
    for (int j = 0; j < 16; ++j) acc[j] = 0.f;

    const float* xr = x + (size_t)(t0 + c) * HIDDEN + 8 * h;
    const float* wr = ((c < 16) ? (w1A + (size_t)c * HIDDEN)
                                : (w3A + (size_t)(c - 16) * HIDDEN)) + 8 * h;
    const int kt0 = by * 32 + w * 8;
    #pragma unroll 4
    for (int kt = kt0; kt < kt0 + 8; ++kt) {
        const float* xp = xr + (size_t)kt * 16;
        const float* wp = wr + (size_t)kt * 16;
        float4 a0 = *(const float4*)xp, a1 = *(const float4*)(xp + 4);
        float4 b0 = *(const float4*)wp, b1 = *(const float4*)(wp + 4);
        short8 av = __builtin_bit_cast(short8,
            make_uint4(pk_bf16(a0.x, a0.y), pk_bf16(a0.z, a0.w),
                       pk_bf16(a1.x, a1.y), pk_bf16(a1.z, a1.w)));
        short8 bv = __builtin_bit_cast(short8,
            make_uint4(pk_bf16(b0.x, b0.y), pk_bf16(b0.z, b0.w),
                       pk_bf16(b1.x, b1.y), pk_bf16(b1.z, b1.w)));
        acc = __builtin_amdgcn_mfma_f32_32x32x16_bf16(av, bv, acc, 0, 0, 0);
    }
    #pragma unroll
    for (int j = 0; j < 16; ++j) {
        int row = (j & 3) + 8 * (j >> 2) + 4 * h;
        s_red[w][row][c] = acc[j];
    }
    __syncthreads();
    float* sl = slab + (size_t)by * TOKENS * 32;
    for (int p = tid; p < 1024; p += 256) {
        int row = p >> 5, cc = p & 31;
        float s = s_red[0][row][cc] + s_red[1][row][cc]
                + s_red[2][row][cc] + s_red[3][row][cc];
        sl[(size_t)(t0 + row) * 32 + cc] = s;
    }
}

// ---------------- K1b: sum slabs + A-bias -> packed bf16 B-fragments --------
// 8192 lanes total; output 256 KB h13pk. Runs once; k2's 3584 blocks then
// read 32 B/lane of L2-hot fragments instead of re-summing slabs.
__global__ __launch_bounds__(256) void k1b_combine(
    const float* __restrict__ slab,
    const float* __restrict__ w1Ab, const float* __restrict__ w3Ab,
    uint4* __restrict__ h13pk)
{
    const int g = blockIdx.x * 256 + threadIdx.x;   // 0..8191
    const int l = g & 63, c = l & 31, h = l >> 5;
    const int tt = g >> 6;
    const int token = tt * 32 + c;

    float a[8], b[8];
    {
        float4 a0 = *(const float4*)(w1Ab + 8 * h), a1 = *(const float4*)(w1Ab + 8 * h + 4);
        float4 b0 = *(const float4*)(w3Ab + 8 * h), b1 = *(const float4*)(w3Ab + 8 * h + 4);
        a[0]=a0.x; a[1]=a0.y; a[2]=a0.z; a[3]=a0.w; a[4]=a1.x; a[5]=a1.y; a[6]=a1.z; a[7]=a1.w;
        b[0]=b0.x; b[1]=b0.y; b[2]=b0.z; b[3]=b0.w; b[4]=b1.x; b[5]=b1.y; b[6]=b1.z; b[7]=b1.w;
    }
    #pragma unroll
    for (int s = 0; s < K1_SPLITS; ++s) {
        const float* p = slab + ((size_t)s * TOKENS + token) * 32 + 8 * h;
        float4 v0 = *(const float4*)p,        v1 = *(const float4*)(p + 4);
        float4 u0 = *(const float4*)(p + 16), u1 = *(const float4*)(p + 20);
        a[0]+=v0.x; a[1]+=v0.y; a[2]+=v0.z; a[3]+=v0.w;
        a[4]+=v1.x; a[5]+=v1.y; a[6]+=v1.z; a[7]+=v1.w;
        b[0]+=u0.x; b[1]+=u0.y; b[2]+=u0.z; b[3]+=u0.w;
        b[4]+=u1.x; b[5]+=u1.y; b[6]+=u1.z; b[7]+=u1.w;
    }
    h13pk[(size_t)g * 2]     = make_uint4(pk_bf16(a[0],a[1]), pk_bf16(a[2],a[3]),
                                          pk_bf16(a[4],a[5]), pk_bf16(a[6],a[7]));
    h13pk[(size_t)g * 2 + 1] = make_uint4(pk_bf16(b[0],b[1]), pk_bf16(b[2],b[3]),
                                          pk_bf16(b[4],b[5]), pk_bf16(b[6],b[7]));
}

// ---------------- K2: fused mid (mfma1, silu, permlane, mfma2) --------------
// grid (128 token-tiles, 28 f-chunks) = 3584 blocks; 4 f-tiles per wave;
// 6 blocks/CU resident. Prologue = one 32 B h13pk read per lane (L2-hot).
__global__ __launch_bounds__(256, 6) void k2_mid(
    const uint4* __restrict__ h13pk,
    const uint4* __restrict__ w1bpk, const uint4* __restrict__ w3bpk,
    const uint4* __restrict__ w2apk,
    const float* __restrict__ b1pk, const float* __restrict__ b3pk,
    float* __restrict__ h2s)
{
    __shared__ float s_acc[4][32][16];
    const int tid = threadIdx.x;
    const int w = tid >> 6, l = tid & 63, c = l & 31, h = l >> 5;
    const int tt = blockIdx.x, t0 = tt * 32, by = blockIdx.y;

    const short8 hA8 = __builtin_bit_cast(short8, h13pk[(size_t)(tt * 64 + l) * 2]);
    const short8 hB8 = __builtin_bit_cast(short8, h13pk[(size_t)(tt * 64 + l) * 2 + 1]);

    f32x16 acc;
    #pragma unroll
    for (int j = 0; j < 16; ++j) acc[j] = 0.f;

    #pragma unroll 2
    for (int it = 0; it < 4; ++it) {
        const int ft = by * 16 + w * 4 + it;
        short8 a1g = __builtin_bit_cast(short8, w1bpk[(size_t)ft * 64 + l]);
        short8 a1u = __builtin_bit_cast(short8, w3bpk[(size_t)ft * 64 + l]);
        short8 b2a = __builtin_bit_cast(short8, w2apk[(size_t)(ft * 2) * 64 + l]);
        short8 b2b = __builtin_bit_cast(short8, w2apk[(size_t)(ft * 2 + 1) * 64 + l]);

        f32x16 Cg = *reinterpret_cast<const f32x16*>(b1pk + ((size_t)ft * 2 + h) * 16);
        f32x16 Cu = *reinterpret_cast<const f32x16*>(b3pk + ((size_t)ft * 2 + h) * 16);

        // D1[f][token] with bias as C-init; weights pre-scaled by 2
        f32x16 d1g = __builtin_amdgcn_mfma_f32_32x32x16_bf16(a1g, hA8, Cg, 0, 0, 0);
        f32x16 d1u = __builtin_amdgcn_mfma_f32_32x32x16_bf16(a1u, hB8, Cu, 0, 0, 0);

        float hv[16];
        #pragma unroll
        for (int j = 0; j < 16; ++j) {
            float gg = d1g[j];
            float sig = __builtin_amdgcn_rcpf(1.f + __expf(-gg));
            hv[j] = gg * sig * d1u[j];
        }
        uint32_t q0 = pk_bf16(hv[0], hv[1]),   q1 = pk_bf16(hv[2], hv[3]);
        uint32_t q2 = pk_bf16(hv[4], hv[5]),   q3 = pk_bf16(hv[6], hv[7]);
        uint32_t q4 = pk_bf16(hv[8], hv[9]),   q5 = pk_bf16(hv[10], hv[11]);
        uint32_t q6 = pk_bf16(hv[12], hv[13]), q7 = pk_bf16(hv[14], hv[15]);
        // DST.high <-> SRC.low: q0=[h0:f01|h1:f89]=A2 reg0, q2=[h0:f45|h1:f1213]=reg2, ...
        asm("v_permlane32_swap_b32 %0, %1" : "+v"(q0), "+v"(q2));
        asm("v_permlane32_swap_b32 %0, %1" : "+v"(q1), "+v"(q3));
        asm("v_permlane32_swap_b32 %0, %1" : "+v"(q4), "+v"(q6));
        asm("v_permlane32_swap_b32 %0, %1" : "+v"(q5), "+v"(q7));
        short8 a2a = __builtin_bit_cast(short8, make_uint4(q0, q1, q2, q3));
        short8 a2b = __builtin_bit_cast(short8, make_uint4(q4, q5, q6, q7));

        acc = __builtin_amdgcn_mfma_f32_32x32x16_bf16(a2a, b2a, acc, 0, 0, 0);
        acc = __builtin_amdgcn_mfma_f32_32x32x16_bf16(a2b, b2b, acc, 0, 0, 0);
    }

    if (c < 16) {
        #pragma unroll
        for (int j = 0; j < 16; ++j)
            s_acc[w][(j & 3) + 8 * (j >> 2) + 4 * h][c] = acc[j];
    }
    __syncthreads();
    for (int p = tid; p < 512; p += 256) {
        int tok = p >> 4, r = p & 15;
        float s = s_acc[0][tok][r] + s_acc[1][tok][r] + s_acc[2][tok][r] + s_acc[3][tok][r];
        h2s[((size_t)by * TOKENS + t0 + tok) * 16 + r] = s;
    }
}

// ---------------- K3: out = ((sum_chunks h2 + w2Ab) @ w2B.T + w2Bb) * 2 -----
__global__ __launch_bounds__(256) void k3_out(
    const float* __restrict__ h2s,
    const float* __restrict__ w2Ab,
    const float* __restrict__ w2B, const float* __restrict__ w2Bb,
    float* __restrict__ out)
{
    __shared__ float s_h2[16][16];
    const int tid = threadIdx.x;
    const int t0 = blockIdx.x * 16;
    const int o0 = blockIdx.y * 1024;

    {
        int t = tid >> 4, r = tid & 15;
        float a = w2Ab[r];
        #pragma unroll 4
        for (int s = 0; s < K2_CHUNKS; ++s)
            a += h2s[((size_t)s * TOKENS + t0 + t) * 16 + r];
        s_h2[t][r] = a;
    }
    __syncthreads();

    const int ob = o0 + tid * 4;
    float w[4][16];
    #pragma unroll
    for (int j = 0; j < 4; ++j) {
        #pragma unroll
        for (int k = 0; k < 4; ++k) {
            float4 v = *(const float4*)(w2B + (size_t)(ob + j) * 16 + k * 4);
            w[j][4*k+0] = v.x; w[j][4*k+1] = v.y;
            w[j][4*k+2] = v.z; w[j][4*k+3] = v.w;
        }
    }
    float4 bb = *(const float4*)(w2Bb + ob);
    float bias[4] = {bb.x, bb.y, bb.z, bb.w};

    for (int t = 0; t < 16; ++t) {
        float res[4];
        #pragma unroll
        for (int j = 0; j < 4; ++j) {
            float a = bias[j];
            #pragma unroll
            for (int r = 0; r < 16; ++r)
                a = fmaf(s_h2[t][r], w[j][r], a);
            res[j] = a * SCALING;
        }
        *(float4*)(out + (size_t)(t0 + t) * 4096 + ob) =
            make_float4(res[0], res[1], res[2], res[3]);
    }
}

extern "C" void kernel_launch(void* const* d_in, const int* in_sizes, int n_in,
                              void* d_out, int out_size, void* d_ws, size_t ws_size,
                              hipStream_t stream) {
    const float* x    = (const float*)d_in[0];
    const float* w1A  = (const float*)d_in[1];
    const float* w1Ab = (const float*)d_in[2];
    const float* w1B  = (const float*)d_in[3];
    const float* w1Bb = (const float*)d_in[4];
    const float* w3A  = (const float*)d_in[5];
    const float* w3Ab = (const float*)d_in[6];
    const float* w3B  = (const float*)d_in[7];
    const float* w3Bb = (const float*)d_in[8];
    const float* w2A  = (const float*)d_in[9];
    const float* w2Ab = (const float*)d_in[10];
    const float* w2B  = (const float*)d_in[11];
    const float* w2Bb = (const float*)d_in[12];
    float* out = (float*)d_out;

    char* ws = (char*)d_ws;
    const uint4* w1bpk = (const uint4*)(ws + OFF_W1BPK);
    const uint4* w3bpk = (const uint4*)(ws + OFF_W3BPK);
    const uint4* w2apk = (const uint4*)(ws + OFF_W2APK);
    const float* b1pk  = (const float*)(ws + OFF_B1PK);
    const float* b3pk  = (const float*)(ws + OFF_B3PK);
    uint4* h13pk = (uint4*)(ws + OFF_H13PK);
    float* slab  = (float*)(ws + OFF_SLAB);
    float* h2s   = (float*)(ws + OFF_H2S);

    p0_pack<<<560, 256, 0, stream>>>(w1B, w3B, w2A, w1Bb, w3Bb, ws);
    k1_xproj<<<dim3(128, K1_SPLITS), 256, 0, stream>>>(x, w1A, w3A, slab);
    k1b_combine<<<32, 256, 0, stream>>>(slab, w1Ab, w3Ab, h13pk);
    k2_mid<<<dim3(128, K2_CHUNKS), 256, 0, stream>>>(h13pk, w1bpk, w3bpk, w2apk,
                                                     b1pk, b3pk, h2s);
    k3_out<<<dim3(256, 4), 256, 0, stream>>>(h2s, w2Ab, w2B, w2Bb, out);
}

// Round 9
// 99.186 us; speedup vs baseline: 1.5622x; 1.1626x over previous
//
#include <hip/hip_runtime.h>

#define TOKENS 4096
#define HIDDEN 4096
#define FFN    14336
#define SCALING 2.0f

typedef short short8 __attribute__((ext_vector_type(8)));
typedef float f32x16 __attribute__((ext_vector_type(16)));

// ---------------------------------------------------------------------------
// 32x32x16 MFMA fragment layouts (HW-verified m74/m101):
//   A frag: lane l (m=l&31, h=l>>5) holds 8 bf16: row m, k = 8h+i
//   B frag: lane l (n=l&31, h=l>>5) holds 8 bf16: col n, k = 8h+i
//   C/D frag: lane l, reg j: row = (j&3)+8*(j>>2)+4h, col = l&31
// v_permlane32_swap_b32 DST,SRC swaps DST.lanes[32:63] <-> SRC.lanes[0:31].
//
// ws layout (bytes):
#define OFF_W1BPK  ((size_t)0)         // [448 f-tiles][64][8 bf16]  2*w1B (A-frag m=f,k=r)
#define OFF_W3BPK  ((size_t)458752)    // [448][64][8]               2*w3B
#define OFF_W2APK  ((size_t)917504)    // [896 16f-subtiles][64][8]  w2A (B-frag k=f,n=r; n>=16 zero)
#define OFF_B1PK   ((size_t)1835008)   // [448][2 halves][16 f32]    2*w1Bb in C-frag order
#define OFF_B3PK   ((size_t)1892352)   // [448][2][16]               2*w3Bb
#define OFF_H13PK  ((size_t)1949696)   // [128 tok-tiles][64][2][8 bf16] h13 B-frags (k1b out)
#define OFF_SLAB   ((size_t)2211840)   // [8 splits][4096][32] f32   k1 partial x-proj (no bias)
#define OFF_H2S    ((size_t)6406144)   // [56 chunks][4096][16] f32  k2 partial h2
// end 21086208 (21.1 MB)

#define K1_SPLITS 8
#define K2_CHUNKS 56

__device__ __forceinline__ uint32_t pk_bf16(float a, float b) {
    uint32_t r;
    asm("v_cvt_pk_bf16_f32 %0, %1, %2" : "=v"(r) : "v"(a), "v"(b));
    return r;
}

// ---------------- P0: pack k2 weights/biases to fragment layouts ------------
__global__ __launch_bounds__(256) void p0_pack(
    const float* __restrict__ w1B, const float* __restrict__ w3B,
    const float* __restrict__ w2A,
    const float* __restrict__ w1Bb, const float* __restrict__ w3Bb,
    char* __restrict__ ws)
{
    const int g = blockIdx.x * 256 + threadIdx.x;

    if (g < 28672) {                       // w1bpk: [ft][l] <- 2*w1B[f=ft*32+c][r=8h+i]
        int l = g & 63, ft = g >> 6, c = l & 31, h = l >> 5;
        const float* s = w1B + (size_t)(ft * 32 + c) * 16 + 8 * h;
        float4 a = *(const float4*)s, b = *(const float4*)(s + 4);
        uint4 o = make_uint4(pk_bf16(a.x * 2.f, a.y * 2.f), pk_bf16(a.z * 2.f, a.w * 2.f),
                             pk_bf16(b.x * 2.f, b.y * 2.f), pk_bf16(b.z * 2.f, b.w * 2.f));
        ((uint4*)(ws + OFF_W1BPK))[g] = o;
    } else if (g < 57344) {                // w3bpk
        int t = g - 28672, l = t & 63, ft = t >> 6, c = l & 31, h = l >> 5;
        const float* s = w3B + (size_t)(ft * 32 + c) * 16 + 8 * h;
        float4 a = *(const float4*)s, b = *(const float4*)(s + 4);
        uint4 o = make_uint4(pk_bf16(a.x * 2.f, a.y * 2.f), pk_bf16(a.z * 2.f, a.w * 2.f),
                             pk_bf16(b.x * 2.f, b.y * 2.f), pk_bf16(b.z * 2.f, b.w * 2.f));
        ((uint4*)(ws + OFF_W3BPK))[t] = o;
    } else if (g < 114688) {               // w2apk: [st][l] <- w2A[r=c][f=st*16+8h+i], zero c>=16
        int t = g - 57344, l = t & 63, st = t >> 6, c = l & 31, h = l >> 5;
        uint4 o = make_uint4(0u, 0u, 0u, 0u);
        if (c < 16) {
            const float* s = w2A + (size_t)c * FFN + st * 16 + 8 * h;
            float4 a = *(const float4*)s, b = *(const float4*)(s + 4);
            o = make_uint4(pk_bf16(a.x, a.y), pk_bf16(a.z, a.w),
                           pk_bf16(b.x, b.y), pk_bf16(b.z, b.w));
        }
        ((uint4*)(ws + OFF_W2APK))[t] = o;
    } else if (g < 129024) {               // b1pk: [ft][h][j] = 2*w1Bb[ft*32+(j&3)+8*(j>>2)+4h]
        int t = g - 114688, ft = t >> 5, rest = t & 31, h = rest >> 4, j = rest & 15;
        int f = ft * 32 + (j & 3) + 8 * (j >> 2) + 4 * h;
        ((float*)(ws + OFF_B1PK))[t] = 2.f * w1Bb[f];
    } else if (g < 143360) {               // b3pk
        int t = g - 129024, ft = t >> 5, rest = t & 31, h = rest >> 4, j = rest & 15;
        int f = ft * 32 + (j & 3) + 8 * (j >> 2) + 4 * h;
        ((float*)(ws + OFF_B3PK))[t] = 2.f * w3Bb[f];
    }
}

// ---------------- K1: x-projection via MFMA, W packed inline ----------------
// 4 waves/block share one 32-token tile; K split 8-way (grid.y) x 4-way
// (waves), 8 k-tiles each. 1024 blocks -> 16 waves/CU for latency hiding.
__global__ __launch_bounds__(256, 2) void k1_xproj(
    const float* __restrict__ x,
    const float* __restrict__ w1A, const float* __restrict__ w3A,
    float* __restrict__ slab)
{
    __shared__ float s_red[4][32][32];   // 16 KB
    const int tid = threadIdx.x;
    const int w = tid >> 6, l = tid & 63, c = l & 31, h = l >> 5;
    const int t0 = blockIdx.x * 32;
    const int by = blockIdx.y;

    f32x16 acc;
    #pragma unroll
    for (int j = 0; j < 16; ++j) acc[j] = 0.f;

    const float* xr = x + (size_t)(t0 + c) * HIDDEN + 8 * h;
    const float* wr = ((c < 16) ? (w1A + (size_t)c * HIDDEN)
                                : (w3A + (size_t)(c - 16) * HIDDEN)) + 8 * h;
    const int kt0 = by * 32 + w * 8;
    #pragma unroll 4
    for (int kt = kt0; kt < kt0 + 8; ++kt) {
        const float* xp = xr + (size_t)kt * 16;
        const float* wp = wr + (size_t)kt * 16;
        float4 a0 = *(const float4*)xp, a1 = *(const float4*)(xp + 4);
        float4 b0 = *(const float4*)wp, b1 = *(const float4*)(wp + 4);
        short8 av = __builtin_bit_cast(short8,
            make_uint4(pk_bf16(a0.x, a0.y), pk_bf16(a0.z, a0.w),
                       pk_bf16(a1.x, a1.y), pk_bf16(a1.z, a1.w)));
        short8 bv = __builtin_bit_cast(short8,
            make_uint4(pk_bf16(b0.x, b0.y), pk_bf16(b0.z, b0.w),
                       pk_bf16(b1.x, b1.y), pk_bf16(b1.z, b1.w)));
        acc = __builtin_amdgcn_mfma_f32_32x32x16_bf16(av, bv, acc, 0, 0, 0);
    }
    #pragma unroll
    for (int j = 0; j < 16; ++j) {
        int row = (j & 3) + 8 * (j >> 2) + 4 * h;
        s_red[w][row][c] = acc[j];
    }
    __syncthreads();
    float* sl = slab + (size_t)by * TOKENS * 32;
    for (int p = tid; p < 1024; p += 256) {
        int row = p >> 5, cc = p & 31;
        float s = s_red[0][row][cc] + s_red[1][row][cc]
                + s_red[2][row][cc] + s_red[3][row][cc];
        sl[(size_t)(t0 + row) * 32 + cc] = s;
    }
}

// ---------------- K1b: sum slabs + A-bias -> packed bf16 B-fragments --------
__global__ __launch_bounds__(256) void k1b_combine(
    const float* __restrict__ slab,
    const float* __restrict__ w1Ab, const float* __restrict__ w3Ab,
    uint4* __restrict__ h13pk)
{
    const int g = blockIdx.x * 256 + threadIdx.x;   // 0..8191
    const int l = g & 63, c = l & 31, h = l >> 5;
    const int tt = g >> 6;
    const int token = tt * 32 + c;

    float a[8], b[8];
    {
        float4 a0 = *(const float4*)(w1Ab + 8 * h), a1 = *(const float4*)(w1Ab + 8 * h + 4);
        float4 b0 = *(const float4*)(w3Ab + 8 * h), b1 = *(const float4*)(w3Ab + 8 * h + 4);
        a[0]=a0.x; a[1]=a0.y; a[2]=a0.z; a[3]=a0.w; a[4]=a1.x; a[5]=a1.y; a[6]=a1.z; a[7]=a1.w;
        b[0]=b0.x; b[1]=b0.y; b[2]=b0.z; b[3]=b0.w; b[4]=b1.x; b[5]=b1.y; b[6]=b1.z; b[7]=b1.w;
    }
    #pragma unroll
    for (int s = 0; s < K1_SPLITS; ++s) {
        const float* p = slab + ((size_t)s * TOKENS + token) * 32 + 8 * h;
        float4 v0 = *(const float4*)p,        v1 = *(const float4*)(p + 4);
        float4 u0 = *(const float4*)(p + 16), u1 = *(const float4*)(p + 20);
        a[0]+=v0.x; a[1]+=v0.y; a[2]+=v0.z; a[3]+=v0.w;
        a[4]+=v1.x; a[5]+=v1.y; a[6]+=v1.z; a[7]+=v1.w;
        b[0]+=u0.x; b[1]+=u0.y; b[2]+=u0.z; b[3]+=u0.w;
        b[4]+=u1.x; b[5]+=u1.y; b[6]+=u1.z; b[7]+=u1.w;
    }
    h13pk[(size_t)g * 2]     = make_uint4(pk_bf16(a[0],a[1]), pk_bf16(a[2],a[3]),
                                          pk_bf16(a[4],a[5]), pk_bf16(a[6],a[7]));
    h13pk[(size_t)g * 2 + 1] = make_uint4(pk_bf16(b[0],b[1]), pk_bf16(b[2],b[3]),
                                          pk_bf16(b[4],b[5]), pk_bf16(b[6],b[7]));
}

// ---------------- K2: fused mid (mfma1, silu, permlane, mfma2) --------------
// Wave-independent: 4-wave blocks, wave w owns chunk by*4+w (8 f-tiles) of its
// token tile. NO LDS, NO barrier -> body length decoupled from occupancy.
// Grid (128, 14) = 1792 blocks = 7168 waves; each writes its own h2s chunk.
__global__ __launch_bounds__(256) void k2_mid(
    const uint4* __restrict__ h13pk,
    const uint4* __restrict__ w1bpk, const uint4* __restrict__ w3bpk,
    const uint4* __restrict__ w2apk,
    const float* __restrict__ b1pk, const float* __restrict__ b3pk,
    float* __restrict__ h2s)
{
    const int tid = threadIdx.x;
    const int w = tid >> 6, l = tid & 63, c = l & 31, h = l >> 5;
    const int tt = blockIdx.x, t0 = tt * 32, by = blockIdx.y;
    const int chunk = by * 4 + w;

    const short8 hA8 = __builtin_bit_cast(short8, h13pk[(size_t)(tt * 64 + l) * 2]);
    const short8 hB8 = __builtin_bit_cast(short8, h13pk[(size_t)(tt * 64 + l) * 2 + 1]);

    f32x16 acc;
    #pragma unroll
    for (int j = 0; j < 16; ++j) acc[j] = 0.f;

    #pragma unroll 2
    for (int it = 0; it < 8; ++it) {
        const int ft = chunk * 8 + it;
        short8 a1g = __builtin_bit_cast(short8, w1bpk[(size_t)ft * 64 + l]);
        short8 a1u = __builtin_bit_cast(short8, w3bpk[(size_t)ft * 64 + l]);
        short8 b2a = __builtin_bit_cast(short8, w2apk[(size_t)(ft * 2) * 64 + l]);
        short8 b2b = __builtin_bit_cast(short8, w2apk[(size_t)(ft * 2 + 1) * 64 + l]);

        f32x16 Cg = *reinterpret_cast<const f32x16*>(b1pk + ((size_t)ft * 2 + h) * 16);
        f32x16 Cu = *reinterpret_cast<const f32x16*>(b3pk + ((size_t)ft * 2 + h) * 16);

        // D1[f][token] with bias as C-init; weights pre-scaled by 2
        f32x16 d1g = __builtin_amdgcn_mfma_f32_32x32x16_bf16(a1g, hA8, Cg, 0, 0, 0);
        f32x16 d1u = __builtin_amdgcn_mfma_f32_32x32x16_bf16(a1u, hB8, Cu, 0, 0, 0);

        float hv[16];
        #pragma unroll
        for (int j = 0; j < 16; ++j) {
            float gg = d1g[j];
            float sig = __builtin_amdgcn_rcpf(1.f + __expf(-gg));
            hv[j] = gg * sig * d1u[j];
        }
        uint32_t q0 = pk_bf16(hv[0], hv[1]),   q1 = pk_bf16(hv[2], hv[3]);
        uint32_t q2 = pk_bf16(hv[4], hv[5]),   q3 = pk_bf16(hv[6], hv[7]);
        uint32_t q4 = pk_bf16(hv[8], hv[9]),   q5 = pk_bf16(hv[10], hv[11]);
        uint32_t q6 = pk_bf16(hv[12], hv[13]), q7 = pk_bf16(hv[14], hv[15]);
        // DST.high <-> SRC.low: q0=[h0:f01|h1:f89]=A2 reg0, q2=[h0:f45|h1:f1213]=reg2, ...
        asm("v_permlane32_swap_b32 %0, %1" : "+v"(q0), "+v"(q2));
        asm("v_permlane32_swap_b32 %0, %1" : "+v"(q1), "+v"(q3));
        asm("v_permlane32_swap_b32 %0, %1" : "+v"(q4), "+v"(q6));
        asm("v_permlane32_swap_b32 %0, %1" : "+v"(q5), "+v"(q7));
        short8 a2a = __builtin_bit_cast(short8, make_uint4(q0, q1, q2, q3));
        short8 a2b = __builtin_bit_cast(short8, make_uint4(q4, q5, q6, q7));

        acc = __builtin_amdgcn_mfma_f32_32x32x16_bf16(a2a, b2a, acc, 0, 0, 0);
        acc = __builtin_amdgcn_mfma_f32_32x32x16_bf16(a2b, b2b, acc, 0, 0, 0);
    }

    // Direct store of this wave's partial h2 (C/D layout; cols >=16 are zero)
    float* hp = h2s + ((size_t)chunk * TOKENS + t0) * 16;
    if (c < 16) {
        #pragma unroll
        for (int j = 0; j < 16; ++j) {
            int row = (j & 3) + 8 * (j >> 2) + 4 * h;
            hp[(size_t)row * 16 + c] = acc[j];
        }
    }
}

// ---------------- K3: out = ((sum_chunks h2 + w2Ab) @ w2B.T + w2Bb) * 2 -----
__global__ __launch_bounds__(256) void k3_out(
    const float* __restrict__ h2s,
    const float* __restrict__ w2Ab,
    const float* __restrict__ w2B, const float* __restrict__ w2Bb,
    float* __restrict__ out)
{
    __shared__ float s_h2[16][16];
    const int tid = threadIdx.x;
    const int t0 = blockIdx.x * 16;
    const int o0 = blockIdx.y * 1024;

    {
        int t = tid >> 4, r = tid & 15;
        float a = w2Ab[r];
        #pragma unroll 4
        for (int s = 0; s < K2_CHUNKS; ++s)
            a += h2s[((size_t)s * TOKENS + t0 + t) * 16 + r];
        s_h2[t][r] = a;
    }
    __syncthreads();

    const int ob = o0 + tid * 4;
    float w[4][16];
    #pragma unroll
    for (int j = 0; j < 4; ++j) {
        #pragma unroll
        for (int k = 0; k < 4; ++k) {
            float4 v = *(const float4*)(w2B + (size_t)(ob + j) * 16 + k * 4);
            w[j][4*k+0] = v.x; w[j][4*k+1] = v.y;
            w[j][4*k+2] = v.z; w[j][4*k+3] = v.w;
        }
    }
    float4 bb = *(const float4*)(w2Bb + ob);
    float bias[4] = {bb.x, bb.y, bb.z, bb.w};

    for (int t = 0; t < 16; ++t) {
        float res[4];
        #pragma unroll
        for (int j = 0; j < 4; ++j) {
            float a = bias[j];
            #pragma unroll
            for (int r = 0; r < 16; ++r)
                a = fmaf(s_h2[t][r], w[j][r], a);
            res[j] = a * SCALING;
        }
        *(float4*)(out + (size_t)(t0 + t) * 4096 + ob) =
            make_float4(res[0], res[1], res[2], res[3]);
    }
}

extern "C" void kernel_launch(void* const* d_in, const int* in_sizes, int n_in,
                              void* d_out, int out_size, void* d_ws, size_t ws_size,
                              hipStream_t stream) {
    const float* x    = (const float*)d_in[0];
    const float* w1A  = (const float*)d_in[1];
    const float* w1Ab = (const float*)d_in[2];
    const float* w1B  = (const float*)d_in[3];
    const float* w1Bb = (const float*)d_in[4];
    const float* w3A  = (const float*)d_in[5];
    const float* w3Ab = (const float*)d_in[6];
    const float* w3B  = (const float*)d_in[7];
    const float* w3Bb = (const float*)d_in[8];
    const float* w2A  = (const float*)d_in[9];
    const float* w2Ab = (const float*)d_in[10];
    const float* w2B  = (const float*)d_in[11];
    const float* w2Bb = (const float*)d_in[12];
    float* out = (float*)d_out;

    char* ws = (char*)d_ws;
    const uint4* w1bpk = (const uint4*)(ws + OFF_W1BPK);
    const uint4* w3bpk = (const uint4*)(ws + OFF_W3BPK);
    const uint4* w2apk = (const uint4*)(ws + OFF_W2APK);
    const float* b1pk  = (const float*)(ws + OFF_B1PK);
    const float* b3pk  = (const float*)(ws + OFF_B3PK);
    uint4* h13pk = (uint4*)(ws + OFF_H13PK);
    float* slab  = (float*)(ws + OFF_SLAB);
    float* h2s   = (float*)(ws + OFF_H2S);

    p0_pack<<<560, 256, 0, stream>>>(w1B, w3B, w2A, w1Bb, w3Bb, ws);
    k1_xproj<<<dim3(128, K1_SPLITS), 256, 0, stream>>>(x, w1A, w3A, slab);
    k1b_combine<<<32, 256, 0, stream>>>(slab, w1Ab, w3Ab, h13pk);
    k2_mid<<<dim3(128, 14), 256, 0, stream>>>(h13pk, w1bpk, w3bpk, w2apk,
                                              b1pk, b3pk, h2s);
    k3_out<<<dim3(256, 4), 256, 0, stream>>>(h2s, w2Ab, w2B, w2Bb, out);
}

// Round 10
// 97.367 us; speedup vs baseline: 1.5914x; 1.0187x over previous
//
#include <hip/hip_runtime.h>

#define TOKENS 4096
#define HIDDEN 4096
#define FFN    14336
#define SCALING 2.0f

typedef short short8 __attribute__((ext_vector_type(8)));
typedef float f32x16 __attribute__((ext_vector_type(16)));

// ---------------------------------------------------------------------------
// 32x32x16 MFMA fragment layouts (HW-verified m74/m101):
//   A frag: lane l (m=l&31, h=l>>5) holds 8 bf16: row m, k = 8h+i
//   B frag: lane l (n=l&31, h=l>>5) holds 8 bf16: col n, k = 8h+i
//   C/D frag: lane l, reg j: row = (j&3)+8*(j>>2)+4h, col = l&31
// v_permlane32_swap_b32 DST,SRC swaps DST.lanes[32:63] <-> SRC.lanes[0:31].
//
// ws layout (bytes):
#define OFF_W1BPK  ((size_t)0)         // [448 f-tiles][64][8 bf16]  2*w1B (A-frag m=f,k=r)
#define OFF_W3BPK  ((size_t)458752)    // [448][64][8]               2*w3B
#define OFF_W2APK  ((size_t)917504)    // [896 16f-subtiles][64][8]  w2A (B-frag k=f,n=r; n>=16 zero)
#define OFF_B1PK   ((size_t)1835008)   // [448][2 halves][16 f32]    2*w1Bb in C-frag order
#define OFF_B3PK   ((size_t)1892352)   // [448][2][16]               2*w3Bb
#define OFF_H13PK  ((size_t)1949696)   // [128 tok-tiles][64][2][8 bf16] h13 B-frags (k1b out)
#define OFF_SLAB   ((size_t)2211840)   // [8 splits][4096][32] f32   k1 partial x-proj (no bias)
#define OFF_H2S    ((size_t)6406144)   // [56 chunks][4096][16] f32  k2 partial h2
#define OFF_H2F    ((size_t)21086208)  // [4096][16] f32             reduced h2 (+w2Ab)
// end 21348352 (21.3 MB)

#define K1_SPLITS 8
#define K2_CHUNKS 56

__device__ __forceinline__ uint32_t pk_bf16(float a, float b) {
    uint32_t r;
    asm("v_cvt_pk_bf16_f32 %0, %1, %2" : "=v"(r) : "v"(a), "v"(b));
    return r;
}

// ---------------- P0: pack k2 weights/biases to fragment layouts ------------
__global__ __launch_bounds__(256) void p0_pack(
    const float* __restrict__ w1B, const float* __restrict__ w3B,
    const float* __restrict__ w2A,
    const float* __restrict__ w1Bb, const float* __restrict__ w3Bb,
    char* __restrict__ ws)
{
    const int g = blockIdx.x * 256 + threadIdx.x;

    if (g < 28672) {                       // w1bpk: [ft][l] <- 2*w1B[f=ft*32+c][r=8h+i]
        int l = g & 63, ft = g >> 6, c = l & 31, h = l >> 5;
        const float* s = w1B + (size_t)(ft * 32 + c) * 16 + 8 * h;
        float4 a = *(const float4*)s, b = *(const float4*)(s + 4);
        uint4 o = make_uint4(pk_bf16(a.x * 2.f, a.y * 2.f), pk_bf16(a.z * 2.f, a.w * 2.f),
                             pk_bf16(b.x * 2.f, b.y * 2.f), pk_bf16(b.z * 2.f, b.w * 2.f));
        ((uint4*)(ws + OFF_W1BPK))[g] = o;
    } else if (g < 57344) {                // w3bpk
        int t = g - 28672, l = t & 63, ft = t >> 6, c = l & 31, h = l >> 5;
        const float* s = w3B + (size_t)(ft * 32 + c) * 16 + 8 * h;
        float4 a = *(const float4*)s, b = *(const float4*)(s + 4);
        uint4 o = make_uint4(pk_bf16(a.x * 2.f, a.y * 2.f), pk_bf16(a.z * 2.f, a.w * 2.f),
                             pk_bf16(b.x * 2.f, b.y * 2.f), pk_bf16(b.z * 2.f, b.w * 2.f));
        ((uint4*)(ws + OFF_W3BPK))[t] = o;
    } else if (g < 114688) {               // w2apk: [st][l] <- w2A[r=c][f=st*16+8h+i], zero c>=16
        int t = g - 57344, l = t & 63, st = t >> 6, c = l & 31, h = l >> 5;
        uint4 o = make_uint4(0u, 0u, 0u, 0u);
        if (c < 16) {
            const float* s = w2A + (size_t)c * FFN + st * 16 + 8 * h;
            float4 a = *(const float4*)s, b = *(const float4*)(s + 4);
            o = make_uint4(pk_bf16(a.x, a.y), pk_bf16(a.z, a.w),
                           pk_bf16(b.x, b.y), pk_bf16(b.z, b.w));
        }
        ((uint4*)(ws + OFF_W2APK))[t] = o;
    } else if (g < 129024) {               // b1pk: [ft][h][j] = 2*w1Bb[ft*32+(j&3)+8*(j>>2)+4h]
        int t = g - 114688, ft = t >> 5, rest = t & 31, h = rest >> 4, j = rest & 15;
        int f = ft * 32 + (j & 3) + 8 * (j >> 2) + 4 * h;
        ((float*)(ws + OFF_B1PK))[t] = 2.f * w1Bb[f];
    } else if (g < 143360) {               // b3pk
        int t = g - 129024, ft = t >> 5, rest = t & 31, h = rest >> 4, j = rest & 15;
        int f = ft * 32 + (j & 3) + 8 * (j >> 2) + 4 * h;
        ((float*)(ws + OFF_B3PK))[t] = 2.f * w3Bb[f];
    }
}

// ---------------- K1: x-projection via MFMA, W packed inline ----------------
__global__ __launch_bounds__(256, 2) void k1_xproj(
    const float* __restrict__ x,
    const float* __restrict__ w1A, const float* __restrict__ w3A,
    float* __restrict__ slab)
{
    __shared__ float s_red[4][32][32];   // 16 KB
    const int tid = threadIdx.x;
    const int w = tid >> 6, l = tid & 63, c = l & 31, h = l >> 5;
    const int t0 = blockIdx.x * 32;
    const int by = blockIdx.y;

    f32x16 acc;
    #pragma unroll
    for (int j = 0; j < 16; ++j) acc[j] = 0.f;

    const float* xr = x + (size_t)(t0 + c) * HIDDEN + 8 * h;
    const float* wr = ((c < 16) ? (w1A + (size_t)c * HIDDEN)
                                : (w3A + (size_t)(c - 16) * HIDDEN)) + 8 * h;
    const int kt0 = by * 32 + w * 8;
    #pragma unroll 4
    for (int kt = kt0; kt < kt0 + 8; ++kt) {
        const float* xp = xr + (size_t)kt * 16;
        const float* wp = wr + (size_t)kt * 16;
        float4 a0 = *(const float4*)xp, a1 = *(const float4*)(xp + 4);
        float4 b0 = *(const float4*)wp, b1 = *(const float4*)(wp + 4);
        short8 av = __builtin_bit_cast(short8,
            make_uint4(pk_bf16(a0.x, a0.y), pk_bf16(a0.z, a0.w),
                       pk_bf16(a1.x, a1.y), pk_bf16(a1.z, a1.w)));
        short8 bv = __builtin_bit_cast(short8,
            make_uint4(pk_bf16(b0.x, b0.y), pk_bf16(b0.z, b0.w),
                       pk_bf16(b1.x, b1.y), pk_bf16(b1.z, b1.w)));
        acc = __builtin_amdgcn_mfma_f32_32x32x16_bf16(av, bv, acc, 0, 0, 0);
    }
    #pragma unroll
    for (int j = 0; j < 16; ++j) {
        int row = (j & 3) + 8 * (j >> 2) + 4 * h;
        s_red[w][row][c] = acc[j];
    }
    __syncthreads();
    float* sl = slab + (size_t)by * TOKENS * 32;
    for (int p = tid; p < 1024; p += 256) {
        int row = p >> 5, cc = p & 31;
        float s = s_red[0][row][cc] + s_red[1][row][cc]
                + s_red[2][row][cc] + s_red[3][row][cc];
        sl[(size_t)(t0 + row) * 32 + cc] = s;
    }
}

// ---------------- K1b: sum slabs + A-bias -> packed bf16 B-fragments --------
__global__ __launch_bounds__(256) void k1b_combine(
    const float* __restrict__ slab,
    const float* __restrict__ w1Ab, const float* __restrict__ w3Ab,
    uint4* __restrict__ h13pk)
{
    const int g = blockIdx.x * 256 + threadIdx.x;   // 0..8191
    const int l = g & 63, c = l & 31, h = l >> 5;
    const int tt = g >> 6;
    const int token = tt * 32 + c;

    float a[8], b[8];
    {
        float4 a0 = *(const float4*)(w1Ab + 8 * h), a1 = *(const float4*)(w1Ab + 8 * h + 4);
        float4 b0 = *(const float4*)(w3Ab + 8 * h), b1 = *(const float4*)(w3Ab + 8 * h + 4);
        a[0]=a0.x; a[1]=a0.y; a[2]=a0.z; a[3]=a0.w; a[4]=a1.x; a[5]=a1.y; a[6]=a1.z; a[7]=a1.w;
        b[0]=b0.x; b[1]=b0.y; b[2]=b0.z; b[3]=b0.w; b[4]=b1.x; b[5]=b1.y; b[6]=b1.z; b[7]=b1.w;
    }
    #pragma unroll
    for (int s = 0; s < K1_SPLITS; ++s) {
        const float* p = slab + ((size_t)s * TOKENS + token) * 32 + 8 * h;
        float4 v0 = *(const float4*)p,        v1 = *(const float4*)(p + 4);
        float4 u0 = *(const float4*)(p + 16), u1 = *(const float4*)(p + 20);
        a[0]+=v0.x; a[1]+=v0.y; a[2]+=v0.z; a[3]+=v0.w;
        a[4]+=v1.x; a[5]+=v1.y; a[6]+=v1.z; a[7]+=v1.w;
        b[0]+=u0.x; b[1]+=u0.y; b[2]+=u0.z; b[3]+=u0.w;
        b[4]+=u1.x; b[5]+=u1.y; b[6]+=u1.z; b[7]+=u1.w;
    }
    h13pk[(size_t)g * 2]     = make_uint4(pk_bf16(a[0],a[1]), pk_bf16(a[2],a[3]),
                                          pk_bf16(a[4],a[5]), pk_bf16(a[6],a[7]));
    h13pk[(size_t)g * 2 + 1] = make_uint4(pk_bf16(b[0],b[1]), pk_bf16(b[2],b[3]),
                                          pk_bf16(b[4],b[5]), pk_bf16(b[6],b[7]));
}

// ---------------- K2: fused mid (mfma1, silu, permlane, mfma2) --------------
// Wave-independent: 4-wave blocks, wave w owns chunk by*4+w (8 f-tiles).
// NO LDS, NO barrier. Grid (128, 14) = 7168 waves, each writes its own chunk.
__global__ __launch_bounds__(256) void k2_mid(
    const uint4* __restrict__ h13pk,
    const uint4* __restrict__ w1bpk, const uint4* __restrict__ w3bpk,
    const uint4* __restrict__ w2apk,
    const float* __restrict__ b1pk, const float* __restrict__ b3pk,
    float* __restrict__ h2s)
{
    const int tid = threadIdx.x;
    const int w = tid >> 6, l = tid & 63, c = l & 31, h = l >> 5;
    const int tt = blockIdx.x, t0 = tt * 32, by = blockIdx.y;
    const int chunk = by * 4 + w;

    const short8 hA8 = __builtin_bit_cast(short8, h13pk[(size_t)(tt * 64 + l) * 2]);
    const short8 hB8 = __builtin_bit_cast(short8, h13pk[(size_t)(tt * 64 + l) * 2 + 1]);

    f32x16 acc;
    #pragma unroll
    for (int j = 0; j < 16; ++j) acc[j] = 0.f;

    #pragma unroll 2
    for (int it = 0; it < 8; ++it) {
        const int ft = chunk * 8 + it;
        short8 a1g = __builtin_bit_cast(short8, w1bpk[(size_t)ft * 64 + l]);
        short8 a1u = __builtin_bit_cast(short8, w3bpk[(size_t)ft * 64 + l]);
        short8 b2a = __builtin_bit_cast(short8, w2apk[(size_t)(ft * 2) * 64 + l]);
        short8 b2b = __builtin_bit_cast(short8, w2apk[(size_t)(ft * 2 + 1) * 64 + l]);

        f32x16 Cg = *reinterpret_cast<const f32x16*>(b1pk + ((size_t)ft * 2 + h) * 16);
        f32x16 Cu = *reinterpret_cast<const f32x16*>(b3pk + ((size_t)ft * 2 + h) * 16);

        // D1[f][token] with bias as C-init; weights pre-scaled by 2
        f32x16 d1g = __builtin_amdgcn_mfma_f32_32x32x16_bf16(a1g, hA8, Cg, 0, 0, 0);
        f32x16 d1u = __builtin_amdgcn_mfma_f32_32x32x16_bf16(a1u, hB8, Cu, 0, 0, 0);

        float hv[16];
        #pragma unroll
        for (int j = 0; j < 16; ++j) {
            float gg = d1g[j];
            float sig = __builtin_amdgcn_rcpf(1.f + __expf(-gg));
            hv[j] = gg * sig * d1u[j];
        }
        uint32_t q0 = pk_bf16(hv[0], hv[1]),   q1 = pk_bf16(hv[2], hv[3]);
        uint32_t q2 = pk_bf16(hv[4], hv[5]),   q3 = pk_bf16(hv[6], hv[7]);
        uint32_t q4 = pk_bf16(hv[8], hv[9]),   q5 = pk_bf16(hv[10], hv[11]);
        uint32_t q6 = pk_bf16(hv[12], hv[13]), q7 = pk_bf16(hv[14], hv[15]);
        // DST.high <-> SRC.low: q0=[h0:f01|h1:f89]=A2 reg0, q2=[h0:f45|h1:f1213]=reg2, ...
        asm("v_permlane32_swap_b32 %0, %1" : "+v"(q0), "+v"(q2));
        asm("v_permlane32_swap_b32 %0, %1" : "+v"(q1), "+v"(q3));
        asm("v_permlane32_swap_b32 %0, %1" : "+v"(q4), "+v"(q6));
        asm("v_permlane32_swap_b32 %0, %1" : "+v"(q5), "+v"(q7));
        short8 a2a = __builtin_bit_cast(short8, make_uint4(q0, q1, q2, q3));
        short8 a2b = __builtin_bit_cast(short8, make_uint4(q4, q5, q6, q7));

        acc = __builtin_amdgcn_mfma_f32_32x32x16_bf16(a2a, b2a, acc, 0, 0, 0);
        acc = __builtin_amdgcn_mfma_f32_32x32x16_bf16(a2b, b2b, acc, 0, 0, 0);
    }

    // Direct store of this wave's partial h2 (C/D layout; cols >=16 are zero)
    float* hp = h2s + ((size_t)chunk * TOKENS + t0) * 16;
    if (c < 16) {
        #pragma unroll
        for (int j = 0; j < 16; ++j) {
            int row = (j & 3) + 8 * (j >> 2) + 4 * h;
            hp[(size_t)row * 16 + c] = acc[j];
        }
    }
}

// ---------------- K2b: reduce 56 h2 chunks + w2Ab -> h2f --------------------
// 16384 threads, one float4 each; per-chunk wave reads 1 KB contiguous.
__global__ __launch_bounds__(256) void k2b_reduce(
    const float* __restrict__ h2s, const float* __restrict__ w2Ab,
    float* __restrict__ h2f)
{
    const int g = blockIdx.x * 256 + threadIdx.x;   // 0..16383 float4s
    float4 acc = *(const float4*)(w2Ab + (g & 3) * 4);
    #pragma unroll 8
    for (int s = 0; s < K2_CHUNKS; ++s) {
        float4 v = *(const float4*)(h2s + (size_t)s * TOKENS * 16 + (size_t)g * 4);
        acc.x += v.x; acc.y += v.y; acc.z += v.z; acc.w += v.w;
    }
    *(float4*)(h2f + (size_t)g * 4) = acc;
}

// ---------------- K3: out = (h2f @ w2B.T + w2Bb) * 2 ------------------------
// Prologue is now a single 1 KB L2-hot read; body is write-BW-bound.
__global__ __launch_bounds__(256) void k3_out(
    const float* __restrict__ h2f,
    const float* __restrict__ w2B, const float* __restrict__ w2Bb,
    float* __restrict__ out)
{
    __shared__ float s_h2[16][16];
    const int tid = threadIdx.x;
    const int t0 = blockIdx.x * 16;
    const int o0 = blockIdx.y * 1024;

    {
        int t = tid >> 4, r = tid & 15;
        s_h2[t][r] = h2f[(size_t)(t0 + t) * 16 + r];
    }
    __syncthreads();

    const int ob = o0 + tid * 4;
    float w[4][16];
    #pragma unroll
    for (int j = 0; j < 4; ++j) {
        #pragma unroll
        for (int k = 0; k < 4; ++k) {
            float4 v = *(const float4*)(w2B + (size_t)(ob + j) * 16 + k * 4);
            w[j][4*k+0] = v.x; w[j][4*k+1] = v.y;
            w[j][4*k+2] = v.z; w[j][4*k+3] = v.w;
        }
    }
    float4 bb = *(const float4*)(w2Bb + ob);
    float bias[4] = {bb.x, bb.y, bb.z, bb.w};

    for (int t = 0; t < 16; ++t) {
        float res[4];
        #pragma unroll
        for (int j = 0; j < 4; ++j) {
            float a = bias[j];
            #pragma unroll
            for (int r = 0; r < 16; ++r)
                a = fmaf(s_h2[t][r], w[j][r], a);
            res[j] = a * SCALING;
        }
        *(float4*)(out + (size_t)(t0 + t) * 4096 + ob) =
            make_float4(res[0], res[1], res[2], res[3]);
    }
}

extern "C" void kernel_launch(void* const* d_in, const int* in_sizes, int n_in,
                              void* d_out, int out_size, void* d_ws, size_t ws_size,
                              hipStream_t stream) {
    const float* x    = (const float*)d_in[0];
    const float* w1A  = (const float*)d_in[1];
    const float* w1Ab = (const float*)d_in[2];
    const float* w1B  = (const float*)d_in[3];
    const float* w1Bb = (const float*)d_in[4];
    const float* w3A  = (const float*)d_in[5];
    const float* w3Ab = (const float*)d_in[6];
    const float* w3B  = (const float*)d_in[7];
    const float* w3Bb = (const float*)d_in[8];
    const float* w2A  = (const float*)d_in[9];
    const float* w2Ab = (const float*)d_in[10];
    const float* w2B  = (const float*)d_in[11];
    const float* w2Bb = (const float*)d_in[12];
    float* out = (float*)d_out;

    char* ws = (char*)d_ws;
    const uint4* w1bpk = (const uint4*)(ws + OFF_W1BPK);
    const uint4* w3bpk = (const uint4*)(ws + OFF_W3BPK);
    const uint4* w2apk = (const uint4*)(ws + OFF_W2APK);
    const float* b1pk  = (const float*)(ws + OFF_B1PK);
    const float* b3pk  = (const float*)(ws + OFF_B3PK);
    uint4* h13pk = (uint4*)(ws + OFF_H13PK);
    float* slab  = (float*)(ws + OFF_SLAB);
    float* h2s   = (float*)(ws + OFF_H2S);
    float* h2f   = (float*)(ws + OFF_H2F);

    p0_pack<<<560, 256, 0, stream>>>(w1B, w3B, w2A, w1Bb, w3Bb, ws);
    k1_xproj<<<dim3(128, K1_SPLITS), 256, 0, stream>>>(x, w1A, w3A, slab);
    k1b_combine<<<32, 256, 0, stream>>>(slab, w1Ab, w3Ab, h13pk);
    k2_mid<<<dim3(128, 14), 256, 0, stream>>>(h13pk, w1bpk, w3bpk, w2apk,
                                              b1pk, b3pk, h2s);
    k2b_reduce<<<64, 256, 0, stream>>>(h2s, w2Ab, h2f);
    k3_out<<<dim3(256, 4), 256, 0, stream>>>(h2f, w2B, w2Bb, out);
}

// Round 11
// 95.971 us; speedup vs baseline: 1.6145x; 1.0145x over previous
//
#include <hip/hip_runtime.h>

#define TOKENS 4096
#define HIDDEN 4096
#define FFN    14336
#define SCALING 2.0f

typedef short short8 __attribute__((ext_vector_type(8)));
typedef float f32x16 __attribute__((ext_vector_type(16)));

// ---------------------------------------------------------------------------
// 32x32x16 MFMA fragment layouts (HW-verified m74/m101):
//   A frag: lane l (m=l&31, h=l>>5) holds 8 bf16: row m, k = 8h+i
//   B frag: lane l (n=l&31, h=l>>5) holds 8 bf16: col n, k = 8h+i
//   C/D frag: lane l, reg j: row = (j&3)+8*(j>>2)+4h, col = l&31
// v_permlane32_swap_b32 DST,SRC swaps DST.lanes[32:63] <-> SRC.lanes[0:31].
//
// ws layout (bytes):
#define OFF_W1BPK  ((size_t)0)         // [448 f-tiles][64][8 bf16]  2*w1B (A-frag m=f,k=r)
#define OFF_W3BPK  ((size_t)458752)    // [448][64][8]               2*w3B
#define OFF_W2APK  ((size_t)917504)    // [896 16f-subtiles][64][8]  w2A (B-frag k=f,n=r; n>=16 zero)
#define OFF_B1PK   ((size_t)1835008)   // [448][2 halves][16 f32]    2*w1Bb in C-frag order
#define OFF_B3PK   ((size_t)1892352)   // [448][2][16]               2*w3Bb
#define OFF_H13PK  ((size_t)1949696)   // [128 tok-tiles][64][2][8 bf16] h13 B-frags (k1b out)
#define OFF_SLAB   ((size_t)2211840)   // [8 splits][4096][32] f32   k1 partial x-proj (no bias)
#define OFF_H2S    ((size_t)6406144)   // [56 chunks][4096][16] f32  k2 partial h2
#define OFF_H2P    ((size_t)21086208)  // [8 cgroups][16384] float4  partial-reduced h2
// end 23183360 (23.2 MB)

#define K1_SPLITS 8
#define K2_CHUNKS 56
#define RED_GROUPS 8
#define RED_PER_GROUP 7

__device__ __forceinline__ uint32_t pk_bf16(float a, float b) {
    uint32_t r;
    asm("v_cvt_pk_bf16_f32 %0, %1, %2" : "=v"(r) : "v"(a), "v"(b));
    return r;
}

// ---------------- P0: pack k2 weights/biases to fragment layouts ------------
__global__ __launch_bounds__(256) void p0_pack(
    const float* __restrict__ w1B, const float* __restrict__ w3B,
    const float* __restrict__ w2A,
    const float* __restrict__ w1Bb, const float* __restrict__ w3Bb,
    char* __restrict__ ws)
{
    const int g = blockIdx.x * 256 + threadIdx.x;

    if (g < 28672) {                       // w1bpk: [ft][l] <- 2*w1B[f=ft*32+c][r=8h+i]
        int l = g & 63, ft = g >> 6, c = l & 31, h = l >> 5;
        const float* s = w1B + (size_t)(ft * 32 + c) * 16 + 8 * h;
        float4 a = *(const float4*)s, b = *(const float4*)(s + 4);
        uint4 o = make_uint4(pk_bf16(a.x * 2.f, a.y * 2.f), pk_bf16(a.z * 2.f, a.w * 2.f),
                             pk_bf16(b.x * 2.f, b.y * 2.f), pk_bf16(b.z * 2.f, b.w * 2.f));
        ((uint4*)(ws + OFF_W1BPK))[g] = o;
    } else if (g < 57344) {                // w3bpk
        int t = g - 28672, l = t & 63, ft = t >> 6, c = l & 31, h = l >> 5;
        const float* s = w3B + (size_t)(ft * 32 + c) * 16 + 8 * h;
        float4 a = *(const float4*)s, b = *(const float4*)(s + 4);
        uint4 o = make_uint4(pk_bf16(a.x * 2.f, a.y * 2.f), pk_bf16(a.z * 2.f, a.w * 2.f),
                             pk_bf16(b.x * 2.f, b.y * 2.f), pk_bf16(b.z * 2.f, b.w * 2.f));
        ((uint4*)(ws + OFF_W3BPK))[t] = o;
    } else if (g < 114688) {               // w2apk: [st][l] <- w2A[r=c][f=st*16+8h+i], zero c>=16
        int t = g - 57344, l = t & 63, st = t >> 6, c = l & 31, h = l >> 5;
        uint4 o = make_uint4(0u, 0u, 0u, 0u);
        if (c < 16) {
            const float* s = w2A + (size_t)c * FFN + st * 16 + 8 * h;
            float4 a = *(const float4*)s, b = *(const float4*)(s + 4);
            o = make_uint4(pk_bf16(a.x, a.y), pk_bf16(a.z, a.w),
                           pk_bf16(b.x, b.y), pk_bf16(b.z, b.w));
        }
        ((uint4*)(ws + OFF_W2APK))[t] = o;
    } else if (g < 129024) {               // b1pk: [ft][h][j] = 2*w1Bb[ft*32+(j&3)+8*(j>>2)+4h]
        int t = g - 114688, ft = t >> 5, rest = t & 31, h = rest >> 4, j = rest & 15;
        int f = ft * 32 + (j & 3) + 8 * (j >> 2) + 4 * h;
        ((float*)(ws + OFF_B1PK))[t] = 2.f * w1Bb[f];
    } else if (g < 143360) {               // b3pk
        int t = g - 129024, ft = t >> 5, rest = t & 31, h = rest >> 4, j = rest & 15;
        int f = ft * 32 + (j & 3) + 8 * (j >> 2) + 4 * h;
        ((float*)(ws + OFF_B3PK))[t] = 2.f * w3Bb[f];
    }
}

// ---------------- K1: x-projection via MFMA, W packed inline ----------------
__global__ __launch_bounds__(256, 2) void k1_xproj(
    const float* __restrict__ x,
    const float* __restrict__ w1A, const float* __restrict__ w3A,
    float* __restrict__ slab)
{
    __shared__ float s_red[4][32][32];   // 16 KB
    const int tid = threadIdx.x;
    const int w = tid >> 6, l = tid & 63, c = l & 31, h = l >> 5;
    const int t0 = blockIdx.x * 32;
    const int by = blockIdx.y;

    f32x16 acc;
    #pragma unroll
    for (int j = 0; j < 16; ++j) acc[j] = 0.f;

    const float* xr = x + (size_t)(t0 + c) * HIDDEN + 8 * h;
    const float* wr = ((c < 16) ? (w1A + (size_t)c * HIDDEN)
                                : (w3A + (size_t)(c - 16) * HIDDEN)) + 8 * h;
    const int kt0 = by * 32 + w * 8;
    #pragma unroll 4
    for (int kt = kt0; kt < kt0 + 8; ++kt) {
        const float* xp = xr + (size_t)kt * 16;
        const float* wp = wr + (size_t)kt * 16;
        float4 a0 = *(const float4*)xp, a1 = *(const float4*)(xp + 4);
        float4 b0 = *(const float4*)wp, b1 = *(const float4*)(wp + 4);
        short8 av = __builtin_bit_cast(short8,
            make_uint4(pk_bf16(a0.x, a0.y), pk_bf16(a0.z, a0.w),
                       pk_bf16(a1.x, a1.y), pk_bf16(a1.z, a1.w)));
        short8 bv = __builtin_bit_cast(short8,
            make_uint4(pk_bf16(b0.x, b0.y), pk_bf16(b0.z, b0.w),
                       pk_bf16(b1.x, b1.y), pk_bf16(b1.z, b1.w)));
        acc = __builtin_amdgcn_mfma_f32_32x32x16_bf16(av, bv, acc, 0, 0, 0);
    }
    #pragma unroll
    for (int j = 0; j < 16; ++j) {
        int row = (j & 3) + 8 * (j >> 2) + 4 * h;
        s_red[w][row][c] = acc[j];
    }
    __syncthreads();
    float* sl = slab + (size_t)by * TOKENS * 32;
    for (int p = tid; p < 1024; p += 256) {
        int row = p >> 5, cc = p & 31;
        float s = s_red[0][row][cc] + s_red[1][row][cc]
                + s_red[2][row][cc] + s_red[3][row][cc];
        sl[(size_t)(t0 + row) * 32 + cc] = s;
    }
}

// ---------------- K1b: sum slabs + A-bias -> packed bf16 B-fragments --------
__global__ __launch_bounds__(256) void k1b_combine(
    const float* __restrict__ slab,
    const float* __restrict__ w1Ab, const float* __restrict__ w3Ab,
    uint4* __restrict__ h13pk)
{
    const int g = blockIdx.x * 256 + threadIdx.x;   // 0..8191
    const int l = g & 63, c = l & 31, h = l >> 5;
    const int tt = g >> 6;
    const int token = tt * 32 + c;

    float a[8], b[8];
    {
        float4 a0 = *(const float4*)(w1Ab + 8 * h), a1 = *(const float4*)(w1Ab + 8 * h + 4);
        float4 b0 = *(const float4*)(w3Ab + 8 * h), b1 = *(const float4*)(w3Ab + 8 * h + 4);
        a[0]=a0.x; a[1]=a0.y; a[2]=a0.z; a[3]=a0.w; a[4]=a1.x; a[5]=a1.y; a[6]=a1.z; a[7]=a1.w;
        b[0]=b0.x; b[1]=b0.y; b[2]=b0.z; b[3]=b0.w; b[4]=b1.x; b[5]=b1.y; b[6]=b1.z; b[7]=b1.w;
    }
    #pragma unroll
    for (int s = 0; s < K1_SPLITS; ++s) {
        const float* p = slab + ((size_t)s * TOKENS + token) * 32 + 8 * h;
        float4 v0 = *(const float4*)p,        v1 = *(const float4*)(p + 4);
        float4 u0 = *(const float4*)(p + 16), u1 = *(const float4*)(p + 20);
        a[0]+=v0.x; a[1]+=v0.y; a[2]+=v0.z; a[3]+=v0.w;
        a[4]+=v1.x; a[5]+=v1.y; a[6]+=v1.z; a[7]+=v1.w;
        b[0]+=u0.x; b[1]+=u0.y; b[2]+=u0.z; b[3]+=u0.w;
        b[4]+=u1.x; b[5]+=u1.y; b[6]+=u1.z; b[7]+=u1.w;
    }
    h13pk[(size_t)g * 2]     = make_uint4(pk_bf16(a[0],a[1]), pk_bf16(a[2],a[3]),
                                          pk_bf16(a[4],a[5]), pk_bf16(a[6],a[7]));
    h13pk[(size_t)g * 2 + 1] = make_uint4(pk_bf16(b[0],b[1]), pk_bf16(b[2],b[3]),
                                          pk_bf16(b[4],b[5]), pk_bf16(b[6],b[7]));
}

// ---------------- K2: fused mid (mfma1, silu, permlane, mfma2) --------------
// Wave-independent: 4-wave blocks, wave w owns chunk by*4+w (8 f-tiles).
// NO LDS, NO barrier. Grid (128, 14) = 7168 waves, each writes its own chunk.
__global__ __launch_bounds__(256) void k2_mid(
    const uint4* __restrict__ h13pk,
    const uint4* __restrict__ w1bpk, const uint4* __restrict__ w3bpk,
    const uint4* __restrict__ w2apk,
    const float* __restrict__ b1pk, const float* __restrict__ b3pk,
    float* __restrict__ h2s)
{
    const int tid = threadIdx.x;
    const int w = tid >> 6, l = tid & 63, c = l & 31, h = l >> 5;
    const int tt = blockIdx.x, t0 = tt * 32, by = blockIdx.y;
    const int chunk = by * 4 + w;

    const short8 hA8 = __builtin_bit_cast(short8, h13pk[(size_t)(tt * 64 + l) * 2]);
    const short8 hB8 = __builtin_bit_cast(short8, h13pk[(size_t)(tt * 64 + l) * 2 + 1]);

    f32x16 acc;
    #pragma unroll
    for (int j = 0; j < 16; ++j) acc[j] = 0.f;

    #pragma unroll 2
    for (int it = 0; it < 8; ++it) {
        const int ft = chunk * 8 + it;
        short8 a1g = __builtin_bit_cast(short8, w1bpk[(size_t)ft * 64 + l]);
        short8 a1u = __builtin_bit_cast(short8, w3bpk[(size_t)ft * 64 + l]);
        short8 b2a = __builtin_bit_cast(short8, w2apk[(size_t)(ft * 2) * 64 + l]);
        short8 b2b = __builtin_bit_cast(short8, w2apk[(size_t)(ft * 2 + 1) * 64 + l]);

        f32x16 Cg = *reinterpret_cast<const f32x16*>(b1pk + ((size_t)ft * 2 + h) * 16);
        f32x16 Cu = *reinterpret_cast<const f32x16*>(b3pk + ((size_t)ft * 2 + h) * 16);

        // D1[f][token] with bias as C-init; weights pre-scaled by 2
        f32x16 d1g = __builtin_amdgcn_mfma_f32_32x32x16_bf16(a1g, hA8, Cg, 0, 0, 0);
        f32x16 d1u = __builtin_amdgcn_mfma_f32_32x32x16_bf16(a1u, hB8, Cu, 0, 0, 0);

        float hv[16];
        #pragma unroll
        for (int j = 0; j < 16; ++j) {
            float gg = d1g[j];
            float sig = __builtin_amdgcn_rcpf(1.f + __expf(-gg));
            hv[j] = gg * sig * d1u[j];
        }
        uint32_t q0 = pk_bf16(hv[0], hv[1]),   q1 = pk_bf16(hv[2], hv[3]);
        uint32_t q2 = pk_bf16(hv[4], hv[5]),   q3 = pk_bf16(hv[6], hv[7]);
        uint32_t q4 = pk_bf16(hv[8], hv[9]),   q5 = pk_bf16(hv[10], hv[11]);
        uint32_t q6 = pk_bf16(hv[12], hv[13]), q7 = pk_bf16(hv[14], hv[15]);
        // DST.high <-> SRC.low: q0=[h0:f01|h1:f89]=A2 reg0, q2=[h0:f45|h1:f1213]=reg2, ...
        asm("v_permlane32_swap_b32 %0, %1" : "+v"(q0), "+v"(q2));
        asm("v_permlane32_swap_b32 %0, %1" : "+v"(q1), "+v"(q3));
        asm("v_permlane32_swap_b32 %0, %1" : "+v"(q4), "+v"(q6));
        asm("v_permlane32_swap_b32 %0, %1" : "+v"(q5), "+v"(q7));
        short8 a2a = __builtin_bit_cast(short8, make_uint4(q0, q1, q2, q3));
        short8 a2b = __builtin_bit_cast(short8, make_uint4(q4, q5, q6, q7));

        acc = __builtin_amdgcn_mfma_f32_32x32x16_bf16(a2a, b2a, acc, 0, 0, 0);
        acc = __builtin_amdgcn_mfma_f32_32x32x16_bf16(a2b, b2b, acc, 0, 0, 0);
    }

    // Direct store of this wave's partial h2 (C/D layout; cols >=16 are zero)
    float* hp = h2s + ((size_t)chunk * TOKENS + t0) * 16;
    if (c < 16) {
        #pragma unroll
        for (int j = 0; j < 16; ++j) {
            int row = (j & 3) + 8 * (j >> 2) + 4 * h;
            hp[(size_t)row * 16 + c] = acc[j];
        }
    }
}

// ---------------- K2b: partial-reduce 56 chunks 8-way -> h2p[8][16384] ------
// 131072 threads (512 blocks, 8 waves/CU); thread (p,cg) sums 7 independent
// strided float4s -- all in flight, no serial chain.
__global__ __launch_bounds__(256) void k2b_partial(
    const float* __restrict__ h2s, float4* __restrict__ h2p)
{
    const int g = blockIdx.x * 256 + threadIdx.x;   // 0..131071
    const int p = g & 16383, cg = g >> 14;
    float4 acc = make_float4(0.f, 0.f, 0.f, 0.f);
    #pragma unroll
    for (int s = cg * RED_PER_GROUP; s < (cg + 1) * RED_PER_GROUP; ++s) {
        float4 v = *(const float4*)(h2s + (size_t)s * TOKENS * 16 + (size_t)p * 4);
        acc.x += v.x; acc.y += v.y; acc.z += v.z; acc.w += v.w;
    }
    h2p[(size_t)cg * 16384 + p] = acc;
}

// ---------------- K3: out = ((sum h2p + w2Ab) @ w2B.T + w2Bb) * 2 -----------
// Prologue: 64 threads sum 8 L2-hot partials (2 MB buffer); body write-bound.
__global__ __launch_bounds__(256) void k3_out(
    const float4* __restrict__ h2p,
    const float* __restrict__ w2Ab,
    const float* __restrict__ w2B, const float* __restrict__ w2Bb,
    float* __restrict__ out)
{
    __shared__ float s_h2[16][16];
    const int tid = threadIdx.x;
    const int t0 = blockIdx.x * 16;
    const int o0 = blockIdx.y * 1024;

    if (tid < 64) {   // 64 float4s cover s_h2 (16 tokens x 4 float4s each)
        float4 acc = *(const float4*)(w2Ab + (tid & 3) * 4);
        #pragma unroll
        for (int cg = 0; cg < RED_GROUPS; ++cg) {
            float4 v = h2p[(size_t)cg * 16384 + t0 * 4 + tid];
            acc.x += v.x; acc.y += v.y; acc.z += v.z; acc.w += v.w;
        }
        ((float4*)s_h2)[tid] = acc;
    }
    __syncthreads();

    const int ob = o0 + tid * 4;
    float w[4][16];
    #pragma unroll
    for (int j = 0; j < 4; ++j) {
        #pragma unroll
        for (int k = 0; k < 4; ++k) {
            float4 v = *(const float4*)(w2B + (size_t)(ob + j) * 16 + k * 4);
            w[j][4*k+0] = v.x; w[j][4*k+1] = v.y;
            w[j][4*k+2] = v.z; w[j][4*k+3] = v.w;
        }
    }
    float4 bb = *(const float4*)(w2Bb + ob);
    float bias[4] = {bb.x, bb.y, bb.z, bb.w};

    for (int t = 0; t < 16; ++t) {
        float res[4];
        #pragma unroll
        for (int j = 0; j < 4; ++j) {
            float a = bias[j];
            #pragma unroll
            for (int r = 0; r < 16; ++r)
                a = fmaf(s_h2[t][r], w[j][r], a);
            res[j] = a * SCALING;
        }
        *(float4*)(out + (size_t)(t0 + t) * 4096 + ob) =
            make_float4(res[0], res[1], res[2], res[3]);
    }
}

extern "C" void kernel_launch(void* const* d_in, const int* in_sizes, int n_in,
                              void* d_out, int out_size, void* d_ws, size_t ws_size,
                              hipStream_t stream) {
    const float* x    = (const float*)d_in[0];
    const float* w1A  = (const float*)d_in[1];
    const float* w1Ab = (const float*)d_in[2];
    const float* w1B  = (const float*)d_in[3];
    const float* w1Bb = (const float*)d_in[4];
    const float* w3A  = (const float*)d_in[5];
    const float* w3Ab = (const float*)d_in[6];
    const float* w3B  = (const float*)d_in[7];
    const float* w3Bb = (const float*)d_in[8];
    const float* w2A  = (const float*)d_in[9];
    const float* w2Ab = (const float*)d_in[10];
    const float* w2B  = (const float*)d_in[11];
    const float* w2Bb = (const float*)d_in[12];
    float* out = (float*)d_out;

    char* ws = (char*)d_ws;
    const uint4* w1bpk = (const uint4*)(ws + OFF_W1BPK);
    const uint4* w3bpk = (const uint4*)(ws + OFF_W3BPK);
    const uint4* w2apk = (const uint4*)(ws + OFF_W2APK);
    const float* b1pk  = (const float*)(ws + OFF_B1PK);
    const float* b3pk  = (const float*)(ws + OFF_B3PK);
    uint4* h13pk = (uint4*)(ws + OFF_H13PK);
    float* slab  = (float*)(ws + OFF_SLAB);
    float* h2s   = (float*)(ws + OFF_H2S);
    float4* h2p  = (float4*)(ws + OFF_H2P);

    p0_pack<<<560, 256, 0, stream>>>(w1B, w3B, w2A, w1Bb, w3Bb, ws);
    k1_xproj<<<dim3(128, K1_SPLITS), 256, 0, stream>>>(x, w1A, w3A, slab);
    k1b_combine<<<32, 256, 0, stream>>>(slab, w1Ab, w3Ab, h13pk);
    k2_mid<<<dim3(128, 14), 256, 0, stream>>>(h13pk, w1bpk, w3bpk, w2apk,
                                              b1pk, b3pk, h2s);
    k2b_partial<<<512, 256, 0, stream>>>(h2s, h2p);
    k3_out<<<dim3(256, 4), 256, 0, stream>>>(h2p, w2Ab, w2B, w2Bb, out);
}

// Round 12
// 91.886 us; speedup vs baseline: 1.6863x; 1.0445x over previous
//
#include <hip/hip_runtime.h>

#define TOKENS 4096
#define HIDDEN 4096
#define FFN    14336
#define SCALING 2.0f

typedef short short8 __attribute__((ext_vector_type(8)));
typedef float f32x16 __attribute__((ext_vector_type(16)));

// ---------------------------------------------------------------------------
// 32x32x16 MFMA fragment layouts (HW-verified m74/m101):
//   A frag: lane l (m=l&31, h=l>>5) holds 8 bf16: row m, k = 8h+i
//   B frag: lane l (n=l&31, h=l>>5) holds 8 bf16: col n, k = 8h+i
//   C/D frag: lane l, reg j: row = (j&3)+8*(j>>2)+4h, col = l&31
// v_permlane32_swap_b32 DST,SRC swaps DST.lanes[32:63] <-> SRC.lanes[0:31].
//
// ws layout (bytes):
#define OFF_W1BPK  ((size_t)0)         // [448 f-tiles][64][8 bf16]  2*w1B (A-frag m=f,k=r)
#define OFF_W3BPK  ((size_t)458752)    // [448][64][8]               2*w3B
#define OFF_W2APK  ((size_t)917504)    // [896 16f-subtiles][64][8]  w2A (B-frag k=f,n=r; n>=16 zero)
#define OFF_B1PK   ((size_t)1835008)   // [448][2 halves][16 f32]    2*w1Bb in C-frag order
#define OFF_B3PK   ((size_t)1892352)   // [448][2][16]               2*w3Bb
#define OFF_H13PK  ((size_t)1949696)   // [128 tok-tiles][64][2][8 bf16] h13 B-frags (k1b out)
#define OFF_SLAB   ((size_t)2211840)   // [8 splits][4096][32] f32   k1 partial x-proj (no bias)
#define OFF_H2F    ((size_t)6406144)   // [4096][16] f32             h2 accumulator (memset 0)
// end 6668288 (6.7 MB)

#define K1_SPLITS 8
#define P0_BLOCKS 560
#define K1_BLOCKS 1024

__device__ __forceinline__ uint32_t pk_bf16(float a, float b) {
    uint32_t r;
    asm("v_cvt_pk_bf16_f32 %0, %1, %2" : "=v"(r) : "v"(a), "v"(b));
    return r;
}

// ---------------- kA: fused weight-pack (blocks 0..559) + x-proj (560..1583)
// The two halves are independent: pack writes ws regions read only by k2/k3;
// xproj reads raw inputs. Fusing removes a dispatch gap and overlaps pack's
// ALU work under xproj's memory-bound phase.
__global__ __launch_bounds__(256, 2) void kA_pack_xproj(
    const float* __restrict__ x,
    const float* __restrict__ w1A, const float* __restrict__ w3A,
    const float* __restrict__ w1B, const float* __restrict__ w3B,
    const float* __restrict__ w2A,
    const float* __restrict__ w1Bb, const float* __restrict__ w3Bb,
    char* __restrict__ ws, float* __restrict__ slab)
{
    __shared__ float s_red[4][32][32];   // 16 KB (xproj path only)
    const int tid = threadIdx.x;

    if (blockIdx.x < P0_BLOCKS) {
        const int g = blockIdx.x * 256 + tid;
        if (g < 28672) {                       // w1bpk: [ft][l] <- 2*w1B[f=ft*32+c][r=8h+i]
            int l = g & 63, ft = g >> 6, c = l & 31, h = l >> 5;
            const float* s = w1B + (size_t)(ft * 32 + c) * 16 + 8 * h;
            float4 a = *(const float4*)s, b = *(const float4*)(s + 4);
            uint4 o = make_uint4(pk_bf16(a.x * 2.f, a.y * 2.f), pk_bf16(a.z * 2.f, a.w * 2.f),
                                 pk_bf16(b.x * 2.f, b.y * 2.f), pk_bf16(b.z * 2.f, b.w * 2.f));
            ((uint4*)(ws + OFF_W1BPK))[g] = o;
        } else if (g < 57344) {                // w3bpk
            int t = g - 28672, l = t & 63, ft = t >> 6, c = l & 31, h = l >> 5;
            const float* s = w3B + (size_t)(ft * 32 + c) * 16 + 8 * h;
            float4 a = *(const float4*)s, b = *(const float4*)(s + 4);
            uint4 o = make_uint4(pk_bf16(a.x * 2.f, a.y * 2.f), pk_bf16(a.z * 2.f, a.w * 2.f),
                                 pk_bf16(b.x * 2.f, b.y * 2.f), pk_bf16(b.z * 2.f, b.w * 2.f));
            ((uint4*)(ws + OFF_W3BPK))[t] = o;
        } else if (g < 114688) {               // w2apk: [st][l] <- w2A[r=c][f=st*16+8h+i], zero c>=16
            int t = g - 57344, l = t & 63, st = t >> 6, c = l & 31, h = l >> 5;
            uint4 o = make_uint4(0u, 0u, 0u, 0u);
            if (c < 16) {
                const float* s = w2A + (size_t)c * FFN + st * 16 + 8 * h;
                float4 a = *(const float4*)s, b = *(const float4*)(s + 4);
                o = make_uint4(pk_bf16(a.x, a.y), pk_bf16(a.z, a.w),
                               pk_bf16(b.x, b.y), pk_bf16(b.z, b.w));
            }
            ((uint4*)(ws + OFF_W2APK))[t] = o;
        } else if (g < 129024) {               // b1pk: [ft][h][j] = 2*w1Bb[ft*32+(j&3)+8*(j>>2)+4h]
            int t = g - 114688, ft = t >> 5, rest = t & 31, h = rest >> 4, j = rest & 15;
            int f = ft * 32 + (j & 3) + 8 * (j >> 2) + 4 * h;
            ((float*)(ws + OFF_B1PK))[t] = 2.f * w1Bb[f];
        } else if (g < 143360) {               // b3pk
            int t = g - 129024, ft = t >> 5, rest = t & 31, h = rest >> 4, j = rest & 15;
            int f = ft * 32 + (j & 3) + 8 * (j >> 2) + 4 * h;
            ((float*)(ws + OFF_B3PK))[t] = 2.f * w3Bb[f];
        }
        return;
    }

    // ---- xproj: 4 waves share one 32-token tile; K split 8-way (b>>7) x
    // 4-way (waves), 8 k-tiles each; LDS reduce -> f32 slab.
    const int b = blockIdx.x - P0_BLOCKS;
    const int tt = b & 127, by = b >> 7;
    const int w = tid >> 6, l = tid & 63, c = l & 31, h = l >> 5;
    const int t0 = tt * 32;

    f32x16 acc;
    #pragma unroll
    for (int j = 0; j < 16; ++j) acc[j] = 0.f;

    const float* xr = x + (size_t)(t0 + c) * HIDDEN + 8 * h;
    const float* wr = ((c < 16) ? (w1A + (size_t)c * HIDDEN)
                                : (w3A + (size_t)(c - 16) * HIDDEN)) + 8 * h;
    const int kt0 = by * 32 + w * 8;
    #pragma unroll 4
    for (int kt = kt0; kt < kt0 + 8; ++kt) {
        const float* xp = xr + (size_t)kt * 16;
        const float* wp = wr + (size_t)kt * 16;
        float4 a0 = *(const float4*)xp, a1 = *(const float4*)(xp + 4);
        float4 b0 = *(const float4*)wp, b1 = *(const float4*)(wp + 4);
        short8 av = __builtin_bit_cast(short8,
            make_uint4(pk_bf16(a0.x, a0.y), pk_bf16(a0.z, a0.w),
                       pk_bf16(a1.x, a1.y), pk_bf16(a1.z, a1.w)));
        short8 bv = __builtin_bit_cast(short8,
            make_uint4(pk_bf16(b0.x, b0.y), pk_bf16(b0.z, b0.w),
                       pk_bf16(b1.x, b1.y), pk_bf16(b1.z, b1.w)));
        acc = __builtin_amdgcn_mfma_f32_32x32x16_bf16(av, bv, acc, 0, 0, 0);
    }
    #pragma unroll
    for (int j = 0; j < 16; ++j) {
        int row = (j & 3) + 8 * (j >> 2) + 4 * h;
        s_red[w][row][c] = acc[j];
    }
    __syncthreads();
    float* sl = slab + (size_t)by * TOKENS * 32;
    for (int p = tid; p < 1024; p += 256) {
        int row = p >> 5, cc = p & 31;
        float s = s_red[0][row][cc] + s_red[1][row][cc]
                + s_red[2][row][cc] + s_red[3][row][cc];
        sl[(size_t)(t0 + row) * 32 + cc] = s;
    }
}

// ---------------- K1b: sum slabs + A-bias -> packed bf16 B-fragments --------
__global__ __launch_bounds__(256) void k1b_combine(
    const float* __restrict__ slab,
    const float* __restrict__ w1Ab, const float* __restrict__ w3Ab,
    uint4* __restrict__ h13pk)
{
    const int g = blockIdx.x * 256 + threadIdx.x;   // 0..8191
    const int l = g & 63, c = l & 31, h = l >> 5;
    const int tt = g >> 6;
    const int token = tt * 32 + c;

    float a[8], b[8];
    {
        float4 a0 = *(const float4*)(w1Ab + 8 * h), a1 = *(const float4*)(w1Ab + 8 * h + 4);
        float4 b0 = *(const float4*)(w3Ab + 8 * h), b1 = *(const float4*)(w3Ab + 8 * h + 4);
        a[0]=a0.x; a[1]=a0.y; a[2]=a0.z; a[3]=a0.w; a[4]=a1.x; a[5]=a1.y; a[6]=a1.z; a[7]=a1.w;
        b[0]=b0.x; b[1]=b0.y; b[2]=b0.z; b[3]=b0.w; b[4]=b1.x; b[5]=b1.y; b[6]=b1.z; b[7]=b1.w;
    }
    #pragma unroll
    for (int s = 0; s < K1_SPLITS; ++s) {
        const float* p = slab + ((size_t)s * TOKENS + token) * 32 + 8 * h;
        float4 v0 = *(const float4*)p,        v1 = *(const float4*)(p + 4);
        float4 u0 = *(const float4*)(p + 16), u1 = *(const float4*)(p + 20);
        a[0]+=v0.x; a[1]+=v0.y; a[2]+=v0.z; a[3]+=v0.w;
        a[4]+=v1.x; a[5]+=v1.y; a[6]+=v1.z; a[7]+=v1.w;
        b[0]+=u0.x; b[1]+=u0.y; b[2]+=u0.z; b[3]+=u0.w;
        b[4]+=u1.x; b[5]+=u1.y; b[6]+=u1.z; b[7]+=u1.w;
    }
    h13pk[(size_t)g * 2]     = make_uint4(pk_bf16(a[0],a[1]), pk_bf16(a[2],a[3]),
                                          pk_bf16(a[4],a[5]), pk_bf16(a[6],a[7]));
    h13pk[(size_t)g * 2 + 1] = make_uint4(pk_bf16(b[0],b[1]), pk_bf16(b[2],b[3]),
                                          pk_bf16(b[4],b[5]), pk_bf16(b[6],b[7]));
}

// ---------------- K2: fused mid (mfma1, silu, permlane, mfma2) --------------
// Grid (128, 14), 4 waves/block: wave w covers f-tiles [by*32+w*8, +8) of its
// token tile. 4-wave LDS reduce, then 512 atomicAdds/block into h2f (zeroed
// by memset). Kills the h2s round-trip and the k2b dispatch.
__global__ __launch_bounds__(256) void k2_mid(
    const uint4* __restrict__ h13pk,
    const uint4* __restrict__ w1bpk, const uint4* __restrict__ w3bpk,
    const uint4* __restrict__ w2apk,
    const float* __restrict__ b1pk, const float* __restrict__ b3pk,
    float* __restrict__ h2f)
{
    __shared__ float s_acc[4][32][16];
    const int tid = threadIdx.x;
    const int w = tid >> 6, l = tid & 63, c = l & 31, h = l >> 5;
    const int tt = blockIdx.x, t0 = tt * 32, by = blockIdx.y;

    const short8 hA8 = __builtin_bit_cast(short8, h13pk[(size_t)(tt * 64 + l) * 2]);
    const short8 hB8 = __builtin_bit_cast(short8, h13pk[(size_t)(tt * 64 + l) * 2 + 1]);

    f32x16 acc;
    #pragma unroll
    for (int j = 0; j < 16; ++j) acc[j] = 0.f;

    #pragma unroll 2
    for (int it = 0; it < 8; ++it) {
        const int ft = by * 32 + w * 8 + it;
        short8 a1g = __builtin_bit_cast(short8, w1bpk[(size_t)ft * 64 + l]);
        short8 a1u = __builtin_bit_cast(short8, w3bpk[(size_t)ft * 64 + l]);
        short8 b2a = __builtin_bit_cast(short8, w2apk[(size_t)(ft * 2) * 64 + l]);
        short8 b2b = __builtin_bit_cast(short8, w2apk[(size_t)(ft * 2 + 1) * 64 + l]);

        f32x16 Cg = *reinterpret_cast<const f32x16*>(b1pk + ((size_t)ft * 2 + h) * 16);
        f32x16 Cu = *reinterpret_cast<const f32x16*>(b3pk + ((size_t)ft * 2 + h) * 16);

        // D1[f][token] with bias as C-init; weights pre-scaled by 2
        f32x16 d1g = __builtin_amdgcn_mfma_f32_32x32x16_bf16(a1g, hA8, Cg, 0, 0, 0);
        f32x16 d1u = __builtin_amdgcn_mfma_f32_32x32x16_bf16(a1u, hB8, Cu, 0, 0, 0);

        float hv[16];
        #pragma unroll
        for (int j = 0; j < 16; ++j) {
            float gg = d1g[j];
            float sig = __builtin_amdgcn_rcpf(1.f + __expf(-gg));
            hv[j] = gg * sig * d1u[j];
        }
        uint32_t q0 = pk_bf16(hv[0], hv[1]),   q1 = pk_bf16(hv[2], hv[3]);
        uint32_t q2 = pk_bf16(hv[4], hv[5]),   q3 = pk_bf16(hv[6], hv[7]);
        uint32_t q4 = pk_bf16(hv[8], hv[9]),   q5 = pk_bf16(hv[10], hv[11]);
        uint32_t q6 = pk_bf16(hv[12], hv[13]), q7 = pk_bf16(hv[14], hv[15]);
        // DST.high <-> SRC.low: q0=[h0:f01|h1:f89]=A2 reg0, q2=[h0:f45|h1:f1213]=reg2, ...
        asm("v_permlane32_swap_b32 %0, %1" : "+v"(q0), "+v"(q2));
        asm("v_permlane32_swap_b32 %0, %1" : "+v"(q1), "+v"(q3));
        asm("v_permlane32_swap_b32 %0, %1" : "+v"(q4), "+v"(q6));
        asm("v_permlane32_swap_b32 %0, %1" : "+v"(q5), "+v"(q7));
        short8 a2a = __builtin_bit_cast(short8, make_uint4(q0, q1, q2, q3));
        short8 a2b = __builtin_bit_cast(short8, make_uint4(q4, q5, q6, q7));

        acc = __builtin_amdgcn_mfma_f32_32x32x16_bf16(a2a, b2a, acc, 0, 0, 0);
        acc = __builtin_amdgcn_mfma_f32_32x32x16_bf16(a2b, b2b, acc, 0, 0, 0);
    }

    if (c < 16) {
        #pragma unroll
        for (int j = 0; j < 16; ++j)
            s_acc[w][(j & 3) + 8 * (j >> 2) + 4 * h][c] = acc[j];
    }
    __syncthreads();
    for (int p = tid; p < 512; p += 256) {
        int tok = p >> 4, r = p & 15;
        float s = s_acc[0][tok][r] + s_acc[1][tok][r] + s_acc[2][tok][r] + s_acc[3][tok][r];
        atomicAdd(&h2f[(size_t)(t0 + tok) * 16 + r], s);
    }
}

// ---------------- K3: out = ((h2f + w2Ab) @ w2B.T + w2Bb) * 2 ---------------
// Prologue: 64 threads read 1 KB of L2-hot h2f; body is write-BW-bound.
__global__ __launch_bounds__(256) void k3_out(
    const float* __restrict__ h2f,
    const float* __restrict__ w2Ab,
    const float* __restrict__ w2B, const float* __restrict__ w2Bb,
    float* __restrict__ out)
{
    __shared__ float s_h2[16][16];
    const int tid = threadIdx.x;
    const int t0 = blockIdx.x * 16;
    const int o0 = blockIdx.y * 1024;

    if (tid < 64) {   // 64 float4s cover s_h2 (16 tokens x 4 float4s each)
        float4 acc = *(const float4*)(h2f + (size_t)t0 * 16 + tid * 4);
        float4 b = *(const float4*)(w2Ab + (tid & 3) * 4);
        acc.x += b.x; acc.y += b.y; acc.z += b.z; acc.w += b.w;
        ((float4*)s_h2)[tid] = acc;
    }
    __syncthreads();

    const int ob = o0 + tid * 4;
    float w[4][16];
    #pragma unroll
    for (int j = 0; j < 4; ++j) {
        #pragma unroll
        for (int k = 0; k < 4; ++k) {
            float4 v = *(const float4*)(w2B + (size_t)(ob + j) * 16 + k * 4);
            w[j][4*k+0] = v.x; w[j][4*k+1] = v.y;
            w[j][4*k+2] = v.z; w[j][4*k+3] = v.w;
        }
    }
    float4 bb = *(const float4*)(w2Bb + ob);
    float bias[4] = {bb.x, bb.y, bb.z, bb.w};

    for (int t = 0; t < 16; ++t) {
        float res[4];
        #pragma unroll
        for (int j = 0; j < 4; ++j) {
            float a = bias[j];
            #pragma unroll
            for (int r = 0; r < 16; ++r)
                a = fmaf(s_h2[t][r], w[j][r], a);
            res[j] = a * SCALING;
        }
        *(float4*)(out + (size_t)(t0 + t) * 4096 + ob) =
            make_float4(res[0], res[1], res[2], res[3]);
    }
}

extern "C" void kernel_launch(void* const* d_in, const int* in_sizes, int n_in,
                              void* d_out, int out_size, void* d_ws, size_t ws_size,
                              hipStream_t stream) {
    const float* x    = (const float*)d_in[0];
    const float* w1A  = (const float*)d_in[1];
    const float* w1Ab = (const float*)d_in[2];
    const float* w1B  = (const float*)d_in[3];
    const float* w1Bb = (const float*)d_in[4];
    const float* w3A  = (const float*)d_in[5];
    const float* w3Ab = (const float*)d_in[6];
    const float* w3B  = (const float*)d_in[7];
    const float* w3Bb = (const float*)d_in[8];
    const float* w2A  = (const float*)d_in[9];
    const float* w2Ab = (const float*)d_in[10];
    const float* w2B  = (const float*)d_in[11];
    const float* w2Bb = (const float*)d_in[12];
    float* out = (float*)d_out;

    char* ws = (char*)d_ws;
    const uint4* w1bpk = (const uint4*)(ws + OFF_W1BPK);
    const uint4* w3bpk = (const uint4*)(ws + OFF_W3BPK);
    const uint4* w2apk = (const uint4*)(ws + OFF_W2APK);
    const float* b1pk  = (const float*)(ws + OFF_B1PK);
    const float* b3pk  = (const float*)(ws + OFF_B3PK);
    uint4* h13pk = (uint4*)(ws + OFF_H13PK);
    float* slab  = (float*)(ws + OFF_SLAB);
    float* h2f   = (float*)(ws + OFF_H2F);

    hipMemsetAsync(h2f, 0, (size_t)TOKENS * 16 * sizeof(float), stream);
    kA_pack_xproj<<<P0_BLOCKS + K1_BLOCKS, 256, 0, stream>>>(
        x, w1A, w3A, w1B, w3B, w2A, w1Bb, w3Bb, ws, slab);
    k1b_combine<<<32, 256, 0, stream>>>(slab, w1Ab, w3Ab, h13pk);
    k2_mid<<<dim3(128, 14), 256, 0, stream>>>(h13pk, w1bpk, w3bpk, w2apk,
                                              b1pk, b3pk, h2f);
    k3_out<<<dim3(256, 4), 256, 0, stream>>>(h2f, w2Ab, w2B, w2Bb, out);
}